// Round 2
// baseline (716.737 us; speedup 1.0000x reference)
//
#include <hip/hip_runtime.h>
#include <hip/hip_bf16.h>

#define G    128
#define MDIM 512
#define NDIM 512
#define DDIM 512
#define MP1  513
#define NP1  513

using short8 = __attribute__((ext_vector_type(8))) short;
using short4v = __attribute__((ext_vector_type(4))) short;
using f32x4 = __attribute__((ext_vector_type(4))) float;

// ---------- Kernel 1: inverse row norms ----------
__global__ __launch_bounds__(256)
void gt_norms_kernel(const float* __restrict__ tra, const float* __restrict__ det,
                     float* __restrict__ inv1, float* __restrict__ inv2) {
    int wave = threadIdx.x >> 6;
    int lane = threadIdx.x & 63;
    long row = (long)blockIdx.x * 4 + wave;           // 0 .. 2*G*512-1
    const long per = (long)G * MDIM;
    const float* src; float* dst; long r;
    if (row < per) { src = tra; dst = inv1; r = row; }
    else           { src = det; dst = inv2; r = row - per; }
    const float4* p = reinterpret_cast<const float4*>(src + r * DDIM);
    float4 x0 = p[lane];
    float4 x1 = p[lane + 64];
    float s = x0.x*x0.x + x0.y*x0.y + x0.z*x0.z + x0.w*x0.w
            + x1.x*x1.x + x1.y*x1.y + x1.z*x1.z + x1.w*x1.w;
    for (int off = 32; off; off >>= 1) s += __shfl_down(s, off);
    if (lane == 0) dst[r] = rsqrtf(s);
}

// ---------- Kernel 2: bf16 MFMA GEMM -> K = -affinity/lambda ----------
#define BK 32
#define LDSS 40   // padded LDS row stride in bf16 elems (80B)

__device__ inline short4v cvt4(float4 f) {
    short4v r;
    r[0] = __builtin_bit_cast(short, __float2bfloat16(f.x));
    r[1] = __builtin_bit_cast(short, __float2bfloat16(f.y));
    r[2] = __builtin_bit_cast(short, __float2bfloat16(f.z));
    r[3] = __builtin_bit_cast(short, __float2bfloat16(f.w));
    return r;
}

__global__ __launch_bounds__(256)
void gt_gemm_kernel(const float* __restrict__ tra, const float* __restrict__ det,
                    const float* __restrict__ inv1, const float* __restrict__ inv2,
                    const float* __restrict__ alpha, const float* __restrict__ eps,
                    float* __restrict__ Kout) {
    __shared__ short As[128 * LDSS];
    __shared__ short Bs[128 * LDSS];
    int g  = blockIdx.z;
    int tm = blockIdx.y, tn = blockIdx.x;
    int t = threadIdx.x;
    int wave = t >> 6, lane = t & 63;
    int wr = wave >> 1, wc = wave & 1;                 // 2x2 waves, 64x64 each
    f32x4 acc[4][4] = {};
    const float* Abase = tra + (size_t)g * MDIM * DDIM + (size_t)(tm * 128) * DDIM;
    const float* Bbase = det + (size_t)g * NDIM * DDIM + (size_t)(tn * 128) * DDIM;
    int srow = t >> 3;     // 0..31
    int scol = t & 7;      // float4 index within 32-float chunk

    for (int kt = 0; kt < DDIM / BK; ++kt) {
        int k0 = kt * BK;
        #pragma unroll
        for (int p = 0; p < 4; ++p) {
            int row = p * 32 + srow;
            float4 a = *reinterpret_cast<const float4*>(Abase + (size_t)row * DDIM + k0 + scol * 4);
            float4 b = *reinterpret_cast<const float4*>(Bbase + (size_t)row * DDIM + k0 + scol * 4);
            *reinterpret_cast<short4v*>(&As[row * LDSS + scol * 4]) = cvt4(a);
            *reinterpret_cast<short4v*>(&Bs[row * LDSS + scol * 4]) = cvt4(b);
        }
        __syncthreads();
        short8 af[4], bfv[4];
        #pragma unroll
        for (int i = 0; i < 4; ++i) {
            int arow = wr * 64 + i * 16 + (lane & 15);
            af[i]  = *reinterpret_cast<const short8*>(&As[arow * LDSS + (lane >> 4) * 8]);
            int brow = wc * 64 + i * 16 + (lane & 15);
            bfv[i] = *reinterpret_cast<const short8*>(&Bs[brow * LDSS + (lane >> 4) * 8]);
        }
        #pragma unroll
        for (int i = 0; i < 4; ++i)
            #pragma unroll
            for (int j = 0; j < 4; ++j)
                acc[i][j] = __builtin_amdgcn_mfma_f32_16x16x32_bf16(af[i], bfv[j], acc[i][j], 0, 0, 0);
        __syncthreads();
    }

    float lam = expf(eps[0]) + 0.03f;
    float nscale = -1.0f / lam;
    size_t outbase = (size_t)g * MP1 * NP1;
    int r0 = (lane >> 4) * 4;
    int c0 = lane & 15;
    #pragma unroll
    for (int i = 0; i < 4; ++i) {
        int row = tm * 128 + wr * 64 + i * 16 + r0;
        #pragma unroll
        for (int j = 0; j < 4; ++j) {
            int col = tn * 128 + wc * 64 + j * 16 + c0;
            float s = nscale * inv2[g * NDIM + col];
            #pragma unroll
            for (int r = 0; r < 4; ++r) {
                float val = acc[i][j][r] * inv1[g * MDIM + row + r] * s;
                Kout[outbase + (size_t)(row + r) * NP1 + col] = val;
            }
        }
    }
}

// ---------- Kernel 3: fill augmented last row/col with -alpha/lambda ----------
__global__ __launch_bounds__(256)
void gt_fill_kernel(const float* __restrict__ alpha, const float* __restrict__ eps,
                    float* __restrict__ Kout) {
    float lam = expf(eps[0]) + 0.03f;
    float val = -alpha[0] / lam;
    int idx = blockIdx.x * 256 + threadIdx.x;
    int g = idx / 1025, r = idx % 1025;
    if (g >= G) return;
    size_t base = (size_t)g * MP1 * NP1;
    if (r < NP1) Kout[base + (size_t)MDIM * NP1 + r] = val;        // last row (incl corner)
    else         Kout[base + (size_t)(r - NP1) * NP1 + NDIM] = val; // last col rows 0..511
}

// ---------- Kernel 4: v_j = log_b_j - log sum_i exp(K_ij + u_i) ----------
__global__ __launch_bounds__(256)
void gt_vstep_kernel(const float* __restrict__ Kmat, const float* __restrict__ u,
                     float* __restrict__ v) {
    __shared__ float su[MP1];
    __shared__ float red[4][64];
    int g = blockIdx.y;
    int j0 = blockIdx.x * 64;
    int t = threadIdx.x;
    for (int i = t; i < MP1; i += 256) su[i] = u[g * MP1 + i];
    __syncthreads();
    int c = t & 63, rg = t >> 6;
    int j = j0 + c;
    float s = 0.f;
    if (j < NP1) {
        const float* col = Kmat + (size_t)g * MP1 * NP1 + j;
        #pragma unroll 4
        for (int i = rg; i < MP1; i += 4)
            s += __expf(col[(size_t)i * NP1] + su[i]);
    }
    red[rg][c] = s;
    __syncthreads();
    if (rg == 0 && j < NP1) {
        float tot = red[0][c] + red[1][c] + red[2][c] + red[3][c];
        float logb = (j == NDIM) ? logf((float)MDIM / (MDIM + NDIM))
                                 : logf(1.0f / (MDIM + NDIM));
        v[g * NP1 + j] = logb - __logf(tot);
    }
}

// ---------- Kernel 5: u_i = log_a_i - log sum_j exp(K_ij + v_j) ----------
__global__ __launch_bounds__(256)
void gt_ustep_kernel(const float* __restrict__ Kmat, const float* __restrict__ v,
                     float* __restrict__ u) {
    __shared__ float sv[NP1];
    int g = blockIdx.y;
    int t = threadIdx.x;
    for (int j = t; j < NP1; j += 256) sv[j] = v[g * NP1 + j];
    __syncthreads();
    int wave = t >> 6, lane = t & 63;
    int i = blockIdx.x * 4 + wave;
    if (i >= MP1) return;
    const float* row = Kmat + (size_t)g * MP1 * NP1 + (size_t)i * NP1;
    float s = 0.f;
    #pragma unroll 4
    for (int j = lane; j < NP1; j += 64)
        s += __expf(row[j] + sv[j]);
    for (int off = 32; off; off >>= 1) s += __shfl_down(s, off);
    if (lane == 0) {
        float loga = (i == MDIM) ? logf((float)NDIM / (MDIM + NDIM))
                                 : logf(1.0f / (MDIM + NDIM));
        u[g * MP1 + i] = loga - __logf(s);
    }
}

// ---------- Kernel 6: p = exp(K + u_i + v_j), in place ----------
__global__ __launch_bounds__(256)
void gt_final_kernel(const float* __restrict__ u, const float* __restrict__ v,
                     float* __restrict__ Kmat) {
    size_t idx = (size_t)blockIdx.x * 256u + threadIdx.x;   // total = 128*263169
    const size_t total = (size_t)G * MP1 * NP1;
    if (idx >= total) return;
    unsigned int g = (unsigned int)(idx / 263169u);
    unsigned int rem = (unsigned int)(idx % 263169u);
    unsigned int i = rem / 513u, j = rem % 513u;
    Kmat[idx] = __expf(Kmat[idx] + u[g * MP1 + i] + v[g * MP1 + j]);
}

extern "C" void kernel_launch(void* const* d_in, const int* in_sizes, int n_in,
                              void* d_out, int out_size, void* d_ws, size_t ws_size,
                              hipStream_t stream) {
    const float* det   = (const float*)d_in[0];
    const float* tra   = (const float*)d_in[1];
    const float* alpha = (const float*)d_in[2];
    const float* eps   = (const float*)d_in[3];
    float* out = (float*)d_out;

    float* inv1 = (float*)d_ws;                // G*512
    float* inv2 = inv1 + G * MDIM;             // G*512
    float* u    = inv2 + G * NDIM;             // G*513
    float* v    = u + G * MP1;                 // G*513

    gt_norms_kernel<<<(2 * G * MDIM) / 4, 256, 0, stream>>>(tra, det, inv1, inv2);
    gt_gemm_kernel<<<dim3(4, 4, G), 256, 0, stream>>>(tra, det, inv1, inv2, alpha, eps, out);
    gt_fill_kernel<<<(G * 1025 + 255) / 256, 256, 0, stream>>>(alpha, eps, out);
    hipMemsetAsync(u, 0, G * MP1 * sizeof(float), stream);
    for (int it = 0; it < 8; ++it) {
        gt_vstep_kernel<<<dim3(9, G), 256, 0, stream>>>(out, u, v);
        gt_ustep_kernel<<<dim3(129, G), 256, 0, stream>>>(out, v, u);
    }
    size_t total = (size_t)G * MP1 * NP1;
    gt_final_kernel<<<(unsigned)((total + 255) / 256), 256, 0, stream>>>(u, v, out);
}

// Round 3
// 715.673 us; speedup vs baseline: 1.0015x; 1.0015x over previous
//
#include <hip/hip_runtime.h>
#include <hip/hip_bf16.h>

#define G    128
#define MDIM 512
#define NDIM 512
#define DDIM 512
#define MP1  513
#define NP1  513

using short8 = __attribute__((ext_vector_type(8))) short;
using short4v = __attribute__((ext_vector_type(4))) short;
using f32x4 = __attribute__((ext_vector_type(4))) float;

// ---------- Kernel 1: inverse row norms ----------
__global__ __launch_bounds__(256)
void gt_norms_kernel(const float* __restrict__ tra, const float* __restrict__ det,
                     float* __restrict__ inv1, float* __restrict__ inv2) {
    int wave = threadIdx.x >> 6;
    int lane = threadIdx.x & 63;
    long row = (long)blockIdx.x * 4 + wave;           // 0 .. 2*G*512-1
    const long per = (long)G * MDIM;
    const float* src; float* dst; long r;
    if (row < per) { src = tra; dst = inv1; r = row; }
    else           { src = det; dst = inv2; r = row - per; }
    const float4* p = reinterpret_cast<const float4*>(src + r * DDIM);
    float4 x0 = p[lane];
    float4 x1 = p[lane + 64];
    float s = x0.x*x0.x + x0.y*x0.y + x0.z*x0.z + x0.w*x0.w
            + x1.x*x1.x + x1.y*x1.y + x1.z*x1.z + x1.w*x1.w;
    for (int off = 32; off; off >>= 1) s += __shfl_down(s, off);
    if (lane == 0) dst[r] = rsqrtf(s);
}

// ---------- Kernel 2: bf16 MFMA GEMM -> Kexp = exp(-affinity/lambda) ----------
#define BK 32
#define LDSS 40   // padded LDS row stride in bf16 elems (80B)

__device__ inline short4v cvt4(float4 f) {
    short4v r;
    r[0] = __builtin_bit_cast(short, __float2bfloat16(f.x));
    r[1] = __builtin_bit_cast(short, __float2bfloat16(f.y));
    r[2] = __builtin_bit_cast(short, __float2bfloat16(f.z));
    r[3] = __builtin_bit_cast(short, __float2bfloat16(f.w));
    return r;
}

__global__ __launch_bounds__(256)
void gt_gemm_kernel(const float* __restrict__ tra, const float* __restrict__ det,
                    const float* __restrict__ inv1, const float* __restrict__ inv2,
                    const float* __restrict__ eps,
                    float* __restrict__ Kout) {
    __shared__ short As[128 * LDSS];
    __shared__ short Bs[128 * LDSS];
    // XCD-aware swizzle: 2048 blocks, 8 XCDs -> each XCD owns 16 consecutive g's
    int bid = blockIdx.x;
    int xcd = bid & 7;
    int slot = bid >> 3;                 // 0..255 per xcd
    int g = xcd * 16 + (slot >> 4);
    int tile = slot & 15;
    int tm = tile >> 2, tn = tile & 3;

    int t = threadIdx.x;
    int wave = t >> 6, lane = t & 63;
    int wr = wave >> 1, wc = wave & 1;                 // 2x2 waves, 64x64 each
    f32x4 acc[4][4] = {};
    const float* Abase = tra + (size_t)g * MDIM * DDIM + (size_t)(tm * 128) * DDIM;
    const float* Bbase = det + (size_t)g * NDIM * DDIM + (size_t)(tn * 128) * DDIM;
    int srow = t >> 3;     // 0..31
    int scol = t & 7;      // float4 index within 32-float chunk

    for (int kt = 0; kt < DDIM / BK; ++kt) {
        int k0 = kt * BK;
        #pragma unroll
        for (int p = 0; p < 4; ++p) {
            int row = p * 32 + srow;
            float4 a = *reinterpret_cast<const float4*>(Abase + (size_t)row * DDIM + k0 + scol * 4);
            float4 b = *reinterpret_cast<const float4*>(Bbase + (size_t)row * DDIM + k0 + scol * 4);
            *reinterpret_cast<short4v*>(&As[row * LDSS + scol * 4]) = cvt4(a);
            *reinterpret_cast<short4v*>(&Bs[row * LDSS + scol * 4]) = cvt4(b);
        }
        __syncthreads();
        short8 af[4], bfv[4];
        #pragma unroll
        for (int i = 0; i < 4; ++i) {
            int arow = wr * 64 + i * 16 + (lane & 15);
            af[i]  = *reinterpret_cast<const short8*>(&As[arow * LDSS + (lane >> 4) * 8]);
            int brow = wc * 64 + i * 16 + (lane & 15);
            bfv[i] = *reinterpret_cast<const short8*>(&Bs[brow * LDSS + (lane >> 4) * 8]);
        }
        #pragma unroll
        for (int i = 0; i < 4; ++i)
            #pragma unroll
            for (int j = 0; j < 4; ++j)
                acc[i][j] = __builtin_amdgcn_mfma_f32_16x16x32_bf16(af[i], bfv[j], acc[i][j], 0, 0, 0);
        __syncthreads();
    }

    float lam = expf(eps[0]) + 0.03f;
    float nscale = -1.0f / lam;
    size_t outbase = (size_t)g * MP1 * NP1;
    int r0 = (lane >> 4) * 4;
    int c0 = lane & 15;
    #pragma unroll
    for (int i = 0; i < 4; ++i) {
        int row = tm * 128 + wr * 64 + i * 16 + r0;
        #pragma unroll
        for (int j = 0; j < 4; ++j) {
            int col = tn * 128 + wc * 64 + j * 16 + c0;
            float s = nscale * inv2[g * NDIM + col];
            #pragma unroll
            for (int r = 0; r < 4; ++r) {
                float val = acc[i][j][r] * inv1[g * MDIM + row + r] * s;
                Kout[outbase + (size_t)(row + r) * NP1 + col] = __expf(val);
            }
        }
    }
}

// ---------- Kernel 3: fill augmented last row/col with exp(-alpha/lambda) ----------
__global__ __launch_bounds__(256)
void gt_fill_kernel(const float* __restrict__ alpha, const float* __restrict__ eps,
                    float* __restrict__ Kout) {
    float lam = expf(eps[0]) + 0.03f;
    float val = __expf(-alpha[0] / lam);
    int idx = blockIdx.x * 256 + threadIdx.x;
    int g = idx / 1025, r = idx % 1025;
    if (g >= G) return;
    size_t base = (size_t)g * MP1 * NP1;
    if (r < NP1) Kout[base + (size_t)MDIM * NP1 + r] = val;        // last row (incl corner)
    else         Kout[base + (size_t)(r - NP1) * NP1 + NDIM] = val; // last col rows 0..511
}

// ---------- Kernel 4: fused linear-domain Sinkhorn (8 iters) + finalize ----------
// One 1024-thread block per graph g. K (=Kexp) is 1.05MB, L2/L3-resident.
// bv_j = b_j / sum_i Ke_ij * au_i ;  au_i = a_i / sum_j Ke_ij * bv_j ; p = Ke*au*bv
__global__ __launch_bounds__(1024)
void gt_sinkhorn_kernel(float* __restrict__ Kall) {
    __shared__ float au[MP1];
    __shared__ float bv[MP1];
    __shared__ float red[1024];
    __shared__ float red2[16];
    const float norm = 1.0f / 1024.0f;   // 1/(M+N)
    const float binw = 0.5f;             // norm * 512

    int g = blockIdx.x;
    float* Kp = Kall + (size_t)g * MP1 * NP1;
    int t = threadIdx.x;
    int lane = t & 63, wv = t >> 6;

    if (t < MP1) au[t] = 1.0f;
    __syncthreads();

    for (int it = 0; it < 8; ++it) {
        // ---- v-step ----
        // column 512 partial: thread t covers row t
        float pb = (t < MP1) ? Kp[(size_t)t * NP1 + 512] * au[t] : 0.f;
        for (int off = 32; off; off >>= 1) pb += __shfl_down(pb, off);
        if (lane == 0) red2[wv] = pb;
        // columns 0..511: 2 threads per column (ii = row parity)
        int jj = t & 511, ii = t >> 9;
        const float* colp = Kp + jj;
        float s = 0.f;
        #pragma unroll 4
        for (int i = ii; i < 512; i += 2)
            s += colp[(size_t)i * NP1] * au[i];
        if (ii == 0) s += colp[(size_t)512 * NP1] * au[512];
        red[t] = s;
        __syncthreads();
        if (t < 512) bv[t] = norm / (red[t] + red[t + 512]);
        if (t == 0) {
            float cs = 0.f;
            #pragma unroll
            for (int w = 0; w < 16; ++w) cs += red2[w];
            bv[512] = binw / cs;
        }
        __syncthreads();
        // ---- u-step ---- (one wave per row, strided)
        for (int r = wv; r < MP1; r += 16) {
            const float* rowp = Kp + (size_t)r * NP1;
            float rs = 0.f;
            #pragma unroll
            for (int k = 0; k < 8; ++k)
                rs += rowp[lane + 64 * k] * bv[lane + 64 * k];
            for (int off = 32; off; off >>= 1) rs += __shfl_down(rs, off);
            if (lane == 0) {
                rs += rowp[512] * bv[512];
                au[r] = ((r == 512) ? binw : norm) / rs;
            }
        }
        __syncthreads();
    }

    // ---- finalize: p = Ke * au_i * bv_j, in place ----
    for (int r = wv; r < MP1; r += 16) {
        float ar = au[r];
        float* rowp = Kp + (size_t)r * NP1;
        for (int j = lane; j < NP1; j += 64)
            rowp[j] *= ar * bv[j];
    }
}

extern "C" void kernel_launch(void* const* d_in, const int* in_sizes, int n_in,
                              void* d_out, int out_size, void* d_ws, size_t ws_size,
                              hipStream_t stream) {
    const float* det   = (const float*)d_in[0];
    const float* tra   = (const float*)d_in[1];
    const float* alpha = (const float*)d_in[2];
    const float* eps   = (const float*)d_in[3];
    float* out = (float*)d_out;

    float* inv1 = (float*)d_ws;                // G*512
    float* inv2 = inv1 + G * MDIM;             // G*512

    gt_norms_kernel<<<(2 * G * MDIM) / 4, 256, 0, stream>>>(tra, det, inv1, inv2);
    gt_gemm_kernel<<<2048, 256, 0, stream>>>(tra, det, inv1, inv2, eps, out);
    gt_fill_kernel<<<(G * 1025 + 255) / 256, 256, 0, stream>>>(alpha, eps, out);
    gt_sinkhorn_kernel<<<G, 1024, 0, stream>>>(out);
}

// Round 4
// 408.258 us; speedup vs baseline: 1.7556x; 1.7530x over previous
//
#include <hip/hip_runtime.h>
#include <hip/hip_bf16.h>

#define G    128
#define MDIM 512
#define NDIM 512
#define DDIM 512
#define MP1  513
#define NP1  513
#define NORMC 0.0009765625f   // 1/(M+N)
#define BINW  0.5f            // NORMC * 512

using short8 = __attribute__((ext_vector_type(8))) short;
using short4v = __attribute__((ext_vector_type(4))) short;
using f32x4 = __attribute__((ext_vector_type(4))) float;

__device__ inline float bf2f(unsigned short u) {
    unsigned int x = ((unsigned int)u) << 16;
    return __builtin_bit_cast(float, x);
}
__device__ inline unsigned short f2bf(float f) {
    return __builtin_bit_cast(unsigned short, __float2bfloat16(f));
}
template<bool BF16>
__device__ inline float loadK(const void* K, size_t idx) {
    if constexpr (BF16) return bf2f(((const unsigned short*)K)[idx]);
    else                return ((const float*)K)[idx];
}

// ---------- Kernel 1: inverse row norms ----------
__global__ __launch_bounds__(256)
void gt_norms_kernel(const float* __restrict__ tra, const float* __restrict__ det,
                     float* __restrict__ inv1, float* __restrict__ inv2) {
    int wave = threadIdx.x >> 6;
    int lane = threadIdx.x & 63;
    long row = (long)blockIdx.x * 4 + wave;
    const long per = (long)G * MDIM;
    const float* src; float* dst; long r;
    if (row < per) { src = tra; dst = inv1; r = row; }
    else           { src = det; dst = inv2; r = row - per; }
    const float4* p = reinterpret_cast<const float4*>(src + r * DDIM);
    float4 x0 = p[lane];
    float4 x1 = p[lane + 64];
    float s = x0.x*x0.x + x0.y*x0.y + x0.z*x0.z + x0.w*x0.w
            + x1.x*x1.x + x1.y*x1.y + x1.z*x1.z + x1.w*x1.w;
    for (int off = 32; off; off >>= 1) s += __shfl_down(s, off);
    if (lane == 0) dst[r] = rsqrtf(s);
}

// ---------- Kernel 2: bf16 MFMA GEMM -> Kexp = exp(-affinity/lambda) ----------
#define BK 32
#define LDSS 40

__device__ inline short4v cvt4(float4 f) {
    short4v r;
    r[0] = __builtin_bit_cast(short, __float2bfloat16(f.x));
    r[1] = __builtin_bit_cast(short, __float2bfloat16(f.y));
    r[2] = __builtin_bit_cast(short, __float2bfloat16(f.z));
    r[3] = __builtin_bit_cast(short, __float2bfloat16(f.w));
    return r;
}

__global__ __launch_bounds__(256)
void gt_gemm_kernel(const float* __restrict__ tra, const float* __restrict__ det,
                    const float* __restrict__ inv1, const float* __restrict__ inv2,
                    const float* __restrict__ eps,
                    float* __restrict__ Koutf, unsigned short* __restrict__ Ke,
                    int bfout) {
    __shared__ short As[128 * LDSS];
    __shared__ short Bs[128 * LDSS];
    int bid = blockIdx.x;
    int xcd = bid & 7;
    int slot = bid >> 3;
    int g = xcd * 16 + (slot >> 4);
    int tile = slot & 15;
    int tm = tile >> 2, tn = tile & 3;

    int t = threadIdx.x;
    int wave = t >> 6, lane = t & 63;
    int wr = wave >> 1, wc = wave & 1;
    f32x4 acc[4][4] = {};
    const float* Abase = tra + (size_t)g * MDIM * DDIM + (size_t)(tm * 128) * DDIM;
    const float* Bbase = det + (size_t)g * NDIM * DDIM + (size_t)(tn * 128) * DDIM;
    int srow = t >> 3;
    int scol = t & 7;

    for (int kt = 0; kt < DDIM / BK; ++kt) {
        int k0 = kt * BK;
        #pragma unroll
        for (int p = 0; p < 4; ++p) {
            int row = p * 32 + srow;
            float4 a = *reinterpret_cast<const float4*>(Abase + (size_t)row * DDIM + k0 + scol * 4);
            float4 b = *reinterpret_cast<const float4*>(Bbase + (size_t)row * DDIM + k0 + scol * 4);
            *reinterpret_cast<short4v*>(&As[row * LDSS + scol * 4]) = cvt4(a);
            *reinterpret_cast<short4v*>(&Bs[row * LDSS + scol * 4]) = cvt4(b);
        }
        __syncthreads();
        short8 af[4], bfv[4];
        #pragma unroll
        for (int i = 0; i < 4; ++i) {
            int arow = wr * 64 + i * 16 + (lane & 15);
            af[i]  = *reinterpret_cast<const short8*>(&As[arow * LDSS + (lane >> 4) * 8]);
            int brow = wc * 64 + i * 16 + (lane & 15);
            bfv[i] = *reinterpret_cast<const short8*>(&Bs[brow * LDSS + (lane >> 4) * 8]);
        }
        #pragma unroll
        for (int i = 0; i < 4; ++i)
            #pragma unroll
            for (int j = 0; j < 4; ++j)
                acc[i][j] = __builtin_amdgcn_mfma_f32_16x16x32_bf16(af[i], bfv[j], acc[i][j], 0, 0, 0);
        __syncthreads();
    }

    float lam = __expf(eps[0]) + 0.03f;
    float nscale = -1.0f / lam;
    size_t outbase = (size_t)g * MP1 * NP1;
    size_t kbase = (size_t)g << 18;      // g*512*512
    int r0 = (lane >> 4) * 4;
    int c0 = lane & 15;
    #pragma unroll
    for (int i = 0; i < 4; ++i) {
        int row = tm * 128 + wr * 64 + i * 16 + r0;
        #pragma unroll
        for (int j = 0; j < 4; ++j) {
            int col = tn * 128 + wc * 64 + j * 16 + c0;
            float s = nscale * inv2[g * NDIM + col];
            #pragma unroll
            for (int r = 0; r < 4; ++r) {
                float pv = __expf(acc[i][j][r] * inv1[g * MDIM + row + r] * s);
                if (bfout) Ke[kbase + (size_t)(row + r) * 512 + col] = f2bf(pv);
                else       Koutf[outbase + (size_t)(row + r) * NP1 + col] = pv;
            }
        }
    }
}

// ---------- init au = 1 ----------
__global__ __launch_bounds__(256)
void gt_init_au(float* __restrict__ au) {
    int i = blockIdx.x * 256 + threadIdx.x;
    if (i < G * MP1) au[i] = 1.0f;
}

// ---------- V-step: bv_j = norm / (sum_i Ke_ij*au_i + val*au_512), j<512 ----------
template<bool BF16>
__global__ __launch_bounds__(512)
void gt_vstep(const void* __restrict__ Kv, const float* __restrict__ alpha,
              const float* __restrict__ eps, const float* __restrict__ au,
              float* __restrict__ bv) {
    __shared__ float au_s[MP1];
    __shared__ float part[4][128];
    int g = blockIdx.y, ct = blockIdx.x;
    int t = threadIdx.x;
    for (int i = t; i < MP1; i += 512) au_s[i] = au[g * MP1 + i];
    __syncthreads();
    int c = t & 127, q = t >> 7;
    int col = ct * 128 + c;
    const size_t RS = BF16 ? 512 : 513;
    size_t base = BF16 ? ((size_t)g << 18) : ((size_t)g * 263169);
    float s = 0.f;
    int r0 = q * 128;
    #pragma unroll 8
    for (int i = 0; i < 128; ++i) {
        float kv = loadK<BF16>(Kv, base + (size_t)(r0 + i) * RS + col);
        s += kv * au_s[r0 + i];
    }
    part[q][c] = s;
    __syncthreads();
    if (t < 128) {
        float lam = __expf(eps[0]) + 0.03f;
        float val = __expf(-alpha[0] / lam);
        float tot = part[0][t] + part[1][t] + part[2][t] + part[3][t] + val * au_s[512];
        bv[g * MP1 + ct * 128 + t] = NORMC / tot;
    }
}

// ---------- U-step: au_i = norm / (sum_j Ke_ij*bv_j + val*bv512) ----------
// Also computes bv512 = binw/(val*S_au_old), au_512 = binw/(val*S_bv),
// and stores bv512 into bv[g][512] (needed by finalize).
template<bool BF16>
__global__ __launch_bounds__(256)
void gt_ustep(const void* __restrict__ Kv, const float* __restrict__ alpha,
              const float* __restrict__ eps, float* __restrict__ bv,
              const float* __restrict__ auOld, float* __restrict__ auNew) {
    __shared__ float bv_s[512];
    __shared__ float red[256];
    __shared__ float sh[2];
    int g = blockIdx.y, rt = blockIdx.x;
    int t = threadIdx.x;
    bv_s[t] = bv[g * MP1 + t];
    bv_s[t + 256] = bv[g * MP1 + t + 256];
    float pa = auOld[g * MP1 + t] + auOld[g * MP1 + t + 256];
    if (t == 0) pa += auOld[g * MP1 + 512];
    red[t] = pa;
    __syncthreads();
    if (t < 128) red[t] += red[t + 128];
    __syncthreads();
    if (t < 64) {
        float r = red[t] + red[t + 64];
        for (int off = 32; off; off >>= 1) r += __shfl_down(r, off);
        if (t == 0) {
            float lam = __expf(eps[0]) + 0.03f;
            float val = __expf(-alpha[0] / lam);
            sh[0] = BINW / (val * r);   // bv512
            sh[1] = val;
        }
    }
    __syncthreads();
    float bv512 = sh[0], val = sh[1];
    float pb = bv_s[t] + bv_s[t + 256];
    red[t] = pb;
    __syncthreads();
    if (t < 128) red[t] += red[t + 128];
    __syncthreads();
    if (t < 64) {
        float r = red[t] + red[t + 64];
        for (int off = 32; off; off >>= 1) r += __shfl_down(r, off);
        if (t == 0) sh[0] = r + bv512;  // S_bv
    }
    __syncthreads();
    float Sbv = sh[0];
    if (rt == 0 && t == 0) {
        auNew[g * MP1 + 512] = BINW / (val * Sbv);
        bv[g * MP1 + 512] = bv512;
    }
    const size_t RS = BF16 ? 512 : 513;
    size_t base = BF16 ? ((size_t)g << 18) : ((size_t)g * 263169);
    int wv = t >> 6, lane = t & 63;
    for (int r = rt * 64 + wv; r < rt * 64 + 64; r += 4) {
        float s = 0.f;
        size_t rb = base + (size_t)r * RS;
        #pragma unroll
        for (int k = 0; k < 8; ++k) {
            int j = lane + 64 * k;
            s += loadK<BF16>(Kv, rb + j) * bv_s[j];
        }
        for (int off = 32; off; off >>= 1) s += __shfl_down(s, off);
        if (lane == 0) auNew[g * MP1 + r] = NORMC / (s + val * bv512);
    }
}

// ---------- Finalize: p = Ke*au_i*bv_j (+ analytic last row/col) ----------
// NOTE: no __restrict__ on Kv/out — in the f32 path they alias (in-place).
template<bool BF16>
__global__ __launch_bounds__(256)
void gt_final(const void* Kv, const float* __restrict__ alpha,
              const float* __restrict__ eps, const float* __restrict__ au,
              const float* __restrict__ bv, float* out) {
    __shared__ float bv_s[MP1];
    __shared__ float au_s[64];
    int g = blockIdx.y, rt = blockIdx.x;
    int t = threadIdx.x;
    bv_s[t] = bv[g * MP1 + t];
    bv_s[t + 256] = bv[g * MP1 + t + 256];
    if (t == 0) bv_s[512] = bv[g * MP1 + 512];
    if (t < 64) au_s[t] = au[g * MP1 + rt * 64 + t];
    __syncthreads();
    float lam = __expf(eps[0]) + 0.03f;
    float val = __expf(-alpha[0] / lam);
    const size_t RS = BF16 ? 512 : 513;
    size_t base = BF16 ? ((size_t)g << 18) : ((size_t)g * 263169);
    size_t obase = (size_t)g * 263169;
    for (int ii = 0; ii < 64; ++ii) {
        int i = rt * 64 + ii;
        float ai = au_s[ii];
        size_t rb = base + (size_t)i * RS;
        size_t ob = obase + (size_t)i * NP1;
        float k0 = loadK<BF16>(Kv, rb + t);
        float k1 = loadK<BF16>(Kv, rb + t + 256);
        out[ob + t] = k0 * ai * bv_s[t];
        out[ob + t + 256] = k1 * ai * bv_s[t + 256];
        if (t == 0) out[ob + 512] = val * ai * bv_s[512];
    }
    if (rt == 7) {
        float a512 = au[g * MP1 + 512];
        size_t ob = obase + (size_t)512 * NP1;
        out[ob + t] = val * a512 * bv_s[t];
        out[ob + t + 256] = val * a512 * bv_s[t + 256];
        if (t == 0) out[ob + 512] = val * a512 * bv_s[512];
    }
}

extern "C" void kernel_launch(void* const* d_in, const int* in_sizes, int n_in,
                              void* d_out, int out_size, void* d_ws, size_t ws_size,
                              hipStream_t stream) {
    const float* det   = (const float*)d_in[0];
    const float* tra   = (const float*)d_in[1];
    const float* alpha = (const float*)d_in[2];
    const float* eps   = (const float*)d_in[3];
    float* out = (float*)d_out;

    float* inv1 = (float*)d_ws;                 // 65536
    float* inv2 = inv1 + 65536;                 // 65536
    float* auA  = inv2 + 65536;                 // 65664
    float* auB  = auA + 65664;                  // 65664
    float* bv   = auB + 65664;                  // 65664
    unsigned short* ke = (unsigned short*)(bv + 65664);  // 512*512*G bf16

    const size_t needFast = 4ull * (2 * 65536 + 3 * 65664) + ((size_t)G << 19);
    const bool fast = ws_size >= needFast;

    gt_norms_kernel<<<(2 * G * MDIM) / 4, 256, 0, stream>>>(tra, det, inv1, inv2);
    gt_gemm_kernel<<<2048, 256, 0, stream>>>(tra, det, inv1, inv2, eps, out, ke, fast ? 1 : 0);
    gt_init_au<<<(G * MP1 + 255) / 256, 256, 0, stream>>>(auA);

    float* cur = auA; float* nxt = auB;
    for (int it = 0; it < 8; ++it) {
        if (fast) {
            gt_vstep<true><<<dim3(4, G), 512, 0, stream>>>((const void*)ke, alpha, eps, cur, bv);
            gt_ustep<true><<<dim3(8, G), 256, 0, stream>>>((const void*)ke, alpha, eps, bv, cur, nxt);
        } else {
            gt_vstep<false><<<dim3(4, G), 512, 0, stream>>>((const void*)out, alpha, eps, cur, bv);
            gt_ustep<false><<<dim3(8, G), 256, 0, stream>>>((const void*)out, alpha, eps, bv, cur, nxt);
        }
        float* tmp = cur; cur = nxt; nxt = tmp;
    }
    if (fast)
        gt_final<true><<<dim3(8, G), 256, 0, stream>>>((const void*)ke, alpha, eps, cur, bv, out);
    else
        gt_final<false><<<dim3(8, G), 256, 0, stream>>>((const void*)out, alpha, eps, cur, bv, out);
}

// Round 5
// 320.750 us; speedup vs baseline: 2.2346x; 1.2728x over previous
//
#include <hip/hip_runtime.h>
#include <hip/hip_bf16.h>

#define G    128
#define MDIM 512
#define NDIM 512
#define DDIM 512
#define NORMC 0.0009765625f   // 1/(M+N)
#define BINW  0.5f            // NORMC * 512
#define PW   516              // P row width (f32): [0..511] colsums, [512] sum(au) partial, [513] au512 (b==0 slot)

using short8 = __attribute__((ext_vector_type(8))) short;
using short4v = __attribute__((ext_vector_type(4))) short;
using f32x4 = __attribute__((ext_vector_type(4))) float;

__device__ inline float bf2f(unsigned short u) {
    unsigned int x = ((unsigned int)u) << 16;
    return __builtin_bit_cast(float, x);
}
__device__ inline unsigned short f2bf(float f) {
    return __builtin_bit_cast(unsigned short, __float2bfloat16(f));
}
__device__ inline short4v cvt4(float4 f) {
    short4v r;
    r[0] = __builtin_bit_cast(short, __float2bfloat16(f.x));
    r[1] = __builtin_bit_cast(short, __float2bfloat16(f.y));
    r[2] = __builtin_bit_cast(short, __float2bfloat16(f.z));
    r[3] = __builtin_bit_cast(short, __float2bfloat16(f.w));
    return r;
}

// ---------- Kernel 1: GEMM (+fused norms) -> Kexp, + iteration-0 column partials ----------
__global__ __launch_bounds__(256)
void gt_gemm_kernel(const float* __restrict__ tra, const float* __restrict__ det,
                    const float* __restrict__ eps,
                    float* __restrict__ Koutf, unsigned short* __restrict__ Ke,
                    float* __restrict__ P1, int bfout)
{
    __shared__ short As[128 * 40];
    __shared__ short Bs[128 * 40];
    __shared__ float rnA[128];
    __shared__ float rnB[128];
    int bid = blockIdx.x;
    int xcd = bid & 7, slot = bid >> 3;
    int g = xcd * 16 + (slot >> 4);
    int tile = slot & 15;
    int tm = tile >> 2, tn = tile & 3;
    int t = threadIdx.x, lane = t & 63, wave = t >> 6;
    int wr = wave >> 1, wc = wave & 1;
    f32x4 acc[4][4] = {};
    const float* Abase = tra + (size_t)g * MDIM * DDIM + (size_t)(tm * 128) * DDIM;
    const float* Bbase = det + (size_t)g * NDIM * DDIM + (size_t)(tn * 128) * DDIM;
    int srow = t >> 3, scol = t & 7;
    float ssA[4] = {0.f, 0.f, 0.f, 0.f};
    float ssB[4] = {0.f, 0.f, 0.f, 0.f};

    for (int kt = 0; kt < 16; ++kt) {
        int k0 = kt * 32;
        #pragma unroll
        for (int p = 0; p < 4; ++p) {
            int row = p * 32 + srow;
            float4 a = *reinterpret_cast<const float4*>(Abase + (size_t)row * DDIM + k0 + scol * 4);
            float4 b = *reinterpret_cast<const float4*>(Bbase + (size_t)row * DDIM + k0 + scol * 4);
            ssA[p] += a.x*a.x + a.y*a.y + a.z*a.z + a.w*a.w;
            ssB[p] += b.x*b.x + b.y*b.y + b.z*b.z + b.w*b.w;
            *reinterpret_cast<short4v*>(&As[row * 40 + scol * 4]) = cvt4(a);
            *reinterpret_cast<short4v*>(&Bs[row * 40 + scol * 4]) = cvt4(b);
        }
        __syncthreads();
        short8 af[4], bfv[4];
        #pragma unroll
        for (int i = 0; i < 4; ++i) {
            int arow = wr * 64 + i * 16 + (lane & 15);
            af[i]  = *reinterpret_cast<const short8*>(&As[arow * 40 + (lane >> 4) * 8]);
            int brow = wc * 64 + i * 16 + (lane & 15);
            bfv[i] = *reinterpret_cast<const short8*>(&Bs[brow * 40 + (lane >> 4) * 8]);
        }
        #pragma unroll
        for (int i = 0; i < 4; ++i)
            #pragma unroll
            for (int j = 0; j < 4; ++j)
                acc[i][j] = __builtin_amdgcn_mfma_f32_16x16x32_bf16(af[i], bfv[j], acc[i][j], 0, 0, 0);
        __syncthreads();
    }

    // fused norms: reduce sum-of-squares across the 8 scol threads sharing a row
    #pragma unroll
    for (int p = 0; p < 4; ++p) {
        float a = ssA[p], b = ssB[p];
        a += __shfl_xor(a, 1); a += __shfl_xor(a, 2); a += __shfl_xor(a, 4);
        b += __shfl_xor(b, 1); b += __shfl_xor(b, 2); b += __shfl_xor(b, 4);
        if (scol == 0) { rnA[p * 32 + srow] = rsqrtf(a); rnB[p * 32 + srow] = rsqrtf(b); }
    }
    __syncthreads();

    float lam = __expf(eps[0]) + 0.03f;
    float nscale = -1.0f / lam;
    size_t kbase = (size_t)g << 18;
    size_t obase = (size_t)g * 263169;
    int r0v = (lane >> 4) * 4;
    int c0 = lane & 15;
    #pragma unroll
    for (int j = 0; j < 4; ++j) {
        int lcol = wc * 64 + j * 16 + c0;
        int colg = tn * 128 + lcol;
        float sc2 = nscale * rnB[lcol];
        float cacc = 0.f;
        #pragma unroll
        for (int i = 0; i < 4; ++i) {
            int lrow = wr * 64 + i * 16 + r0v;
            #pragma unroll
            for (int r = 0; r < 4; ++r) {
                float ev = __expf(acc[i][j][r] * rnA[lrow + r] * sc2);
                cacc += ev;
                int rowg = tm * 128 + lrow + r;
                if (bfout) Ke[kbase + (size_t)rowg * 512 + colg] = f2bf(ev);
                else       Koutf[obase + (size_t)rowg * 513 + colg] = ev;
            }
        }
        cacc += __shfl_down(cacc, 32);
        cacc += __shfl_down(cacc, 16);
        if (lane < 16)
            P1[(size_t)g * (8 * PW) + (size_t)(2 * tm + wr) * PW + tn * 128 + wc * 64 + j * 16 + lane] = cacc;
    }
}

// ---------- Kernel 2 (x8): fused iteration — one pass over K ----------
// head: bv from prev partial colsums; body: au for own rows + new partial colsums
template<bool BF16>
__global__ __launch_bounds__(256)
void gt_iter(const void* __restrict__ Kv,
             const float* __restrict__ alpha, const float* __restrict__ eps,
             const float* __restrict__ Pread, float* __restrict__ Pwrite,
             float* __restrict__ auOut, int first, int writeP)
{
    __shared__ float bv_s[512];
    __shared__ float colpart[4][512];
    __shared__ float rtmp[4];
    __shared__ float scal[1];
    int g = blockIdx.y, rb = blockIdx.x;
    int t = threadIdx.x, lane = t & 63, wv = t >> 6;
    float lam = __expf(eps[0]) + 0.03f;
    float val = __expf(-alpha[0] / lam);
    const float* Pg = Pread + (size_t)g * (8 * PW);
    float au512p = first ? 1.0f : Pg[513];
    float cs0 = 0.f, cs1 = 0.f;
    #pragma unroll
    for (int b = 0; b < 8; ++b) { cs0 += Pg[b * PW + t]; cs1 += Pg[b * PW + t + 256]; }
    float bv0 = NORMC / (cs0 + val * au512p);
    float bv1 = NORMC / (cs1 + val * au512p);
    bv_s[t] = bv0; bv_s[t + 256] = bv1;
    float sb = bv0 + bv1;
    #pragma unroll
    for (int off = 1; off < 64; off <<= 1) sb += __shfl_xor(sb, off);
    if (lane == 0) rtmp[wv] = sb;
    __syncthreads();
    if (t == 0) {
        float S_bv = rtmp[0] + rtmp[1] + rtmp[2] + rtmp[3];
        float S_au_prev;
        if (first) S_au_prev = 513.f;
        else { float s = 0.f; for (int b = 0; b < 8; ++b) s += Pg[b * PW + 512]; S_au_prev = s + au512p; }
        float bv512 = BINW / (val * S_au_prev);
        float au512n = BINW / (val * (S_bv + bv512));
        scal[0] = bv512;
        if (rb == 0) Pwrite[(size_t)g * (8 * PW) + 513] = au512n;
    }
    __syncthreads();
    float bv512 = scal[0];

    float bvr[8];
    #pragma unroll
    for (int k = 0; k < 8; ++k) bvr[k] = bv_s[lane * 8 + k];
    float colacc[8] = {};
    float suma = 0.f;
    const size_t RS = BF16 ? 512 : 513;
    size_t base = BF16 ? ((size_t)g << 18) : ((size_t)g * 263169);
    int rowbase = rb * 64;
    for (int rr = wv; rr < 64; rr += 4) {
        int r = rowbase + rr;
        float kv[8];
        if constexpr (BF16) {
            short8 x = *reinterpret_cast<const short8*>((const unsigned short*)Kv + base + (size_t)r * RS + lane * 8);
            #pragma unroll
            for (int k = 0; k < 8; ++k) kv[k] = bf2f((unsigned short)x[k]);
        } else {
            const float* p = (const float*)Kv + base + (size_t)r * RS + lane * 8;
            #pragma unroll
            for (int k = 0; k < 8; ++k) kv[k] = p[k];
        }
        float dot = 0.f;
        #pragma unroll
        for (int k = 0; k < 8; ++k) dot += kv[k] * bvr[k];
        #pragma unroll
        for (int off = 1; off < 64; off <<= 1) dot += __shfl_xor(dot, off);
        float au_r = NORMC / (dot + val * bv512);
        suma += au_r;
        #pragma unroll
        for (int k = 0; k < 8; ++k) colacc[k] += kv[k] * au_r;
        if (lane == 0) auOut[g * 512 + r] = au_r;
    }
    if (writeP) {
        #pragma unroll
        for (int k = 0; k < 8; ++k) colpart[wv][lane * 8 + k] = colacc[k];
        if (lane == 0) rtmp[wv] = suma;
        __syncthreads();
        float s0 = colpart[0][t] + colpart[1][t] + colpart[2][t] + colpart[3][t];
        float s1 = colpart[0][t + 256] + colpart[1][t + 256] + colpart[2][t + 256] + colpart[3][t + 256];
        float* Pw = Pwrite + (size_t)g * (8 * PW) + (size_t)rb * PW;
        Pw[t] = s0; Pw[t + 256] = s1;
        if (t == 0) Pw[512] = rtmp[0] + rtmp[1] + rtmp[2] + rtmp[3];
    }
}

// ---------- Kernel 3: finalize — bv(7) from P6, p = Ke*au*bv (+ analytic bin row/col) ----------
template<bool BF16>
__global__ __launch_bounds__(256)
void gt_final(const void* Kv, const float* __restrict__ alpha, const float* __restrict__ eps,
              const float* __restrict__ P6, const float* __restrict__ P7,
              const float* __restrict__ au, float* out)
{
    __shared__ float bv_s[512];
    __shared__ float scal[2];
    int g = blockIdx.y, rb = blockIdx.x;
    int t = threadIdx.x, lane = t & 63, wv = t >> 6;
    float lam = __expf(eps[0]) + 0.03f;
    float val = __expf(-alpha[0] / lam);
    const float* Pg = P6 + (size_t)g * (8 * PW);
    float au512_6 = Pg[513];
    float cs0 = 0.f, cs1 = 0.f;
    #pragma unroll
    for (int b = 0; b < 8; ++b) { cs0 += Pg[b * PW + t]; cs1 += Pg[b * PW + t + 256]; }
    bv_s[t] = NORMC / (cs0 + val * au512_6);
    bv_s[t + 256] = NORMC / (cs1 + val * au512_6);
    if (t == 0) {
        float s = 0.f;
        for (int b = 0; b < 8; ++b) s += Pg[b * PW + 512];
        scal[0] = BINW / (val * (s + au512_6));          // bv512(7)
        scal[1] = P7[(size_t)g * (8 * PW) + 513];        // au512(7)
    }
    __syncthreads();
    float bv512 = scal[0], au512_7 = scal[1];
    size_t base = BF16 ? ((size_t)g << 18) : ((size_t)g * 263169);
    size_t obase = (size_t)g * 263169;
    for (int rr = wv; rr < 64; rr += 4) {
        int r = rb * 64 + rr;
        float au_r = au[g * 512 + r];
        float* orow = out + obase + (size_t)r * 513;
        if constexpr (BF16) {
            const unsigned short* kr = (const unsigned short*)Kv + base + (size_t)r * 512;
            #pragma unroll
            for (int k = 0; k < 8; ++k) {
                int j = lane + 64 * k;
                orow[j] = bf2f(kr[j]) * au_r * bv_s[j];
            }
        } else {
            const float* kr = (const float*)Kv + base + (size_t)r * 513;
            #pragma unroll
            for (int k = 0; k < 8; ++k) {
                int j = lane + 64 * k;
                orow[j] = kr[j] * au_r * bv_s[j];
            }
        }
        if (lane == 0) orow[512] = val * au_r * bv512;
    }
    if (rb == 7) {
        float* brow = out + obase + (size_t)512 * 513;
        brow[t] = val * au512_7 * bv_s[t];
        brow[t + 256] = val * au512_7 * bv_s[t + 256];
        if (t == 0) brow[512] = val * au512_7 * bv512;
    }
}

extern "C" void kernel_launch(void* const* d_in, const int* in_sizes, int n_in,
                              void* d_out, int out_size, void* d_ws, size_t ws_size,
                              hipStream_t stream) {
    const float* det   = (const float*)d_in[0];
    const float* tra   = (const float*)d_in[1];
    const float* alpha = (const float*)d_in[2];
    const float* eps   = (const float*)d_in[3];
    float* out = (float*)d_out;

    float* P0 = (float*)d_ws;                       // G*8*PW f32
    float* P1 = P0 + (size_t)G * 8 * PW;            // G*8*PW f32
    float* au = P1 + (size_t)G * 8 * PW;            // G*512 f32
    unsigned short* ke = (unsigned short*)(au + (size_t)G * 512);   // G*512*512 bf16

    size_t smallBytes = ((size_t)2 * G * 8 * PW + (size_t)G * 512) * 4;
    bool fast = ws_size >= smallBytes + ((size_t)G << 19);

    gt_gemm_kernel<<<2048, 256, 0, stream>>>(tra, det, eps, out, ke, P1, fast ? 1 : 0);
    const void* K = fast ? (const void*)ke : (const void*)out;

    float* Pr = P1; float* Pw = P0;
    for (int it = 0; it < 8; ++it) {
        if (fast) gt_iter<true ><<<dim3(8, G), 256, 0, stream>>>(K, alpha, eps, Pr, Pw, au, it == 0 ? 1 : 0, it < 7 ? 1 : 0);
        else      gt_iter<false><<<dim3(8, G), 256, 0, stream>>>(K, alpha, eps, Pr, Pw, au, it == 0 ? 1 : 0, it < 7 ? 1 : 0);
        float* tmp = Pr; Pr = Pw; Pw = tmp;
    }
    // it6 wrote P0 (+au512(6) at [513]); it7 wrote au512(7) into P1[513]
    if (fast) gt_final<true ><<<dim3(8, G), 256, 0, stream>>>(K, alpha, eps, P0, P1, au, out);
    else      gt_final<false><<<dim3(8, G), 256, 0, stream>>>(K, alpha, eps, P0, P1, au, out);
}

// Round 6
// 311.557 us; speedup vs baseline: 2.3005x; 1.0295x over previous
//
#include <hip/hip_runtime.h>
#include <hip/hip_bf16.h>

#define G    128
#define MDIM 512
#define NDIM 512
#define DDIM 512
#define NORMC 0.0009765625f   // 1/(M+N)
#define BINW  0.5f            // NORMC * 512
#define PW   516              // P row width (f32): [0..511] colsums, [512] sum(au) partial, [513] au512 (b==0 slot)

using short8 = __attribute__((ext_vector_type(8))) short;
using short4v = __attribute__((ext_vector_type(4))) short;
using f32x4 = __attribute__((ext_vector_type(4))) float;

__device__ inline float bf2f(unsigned short u) {
    unsigned int x = ((unsigned int)u) << 16;
    return __builtin_bit_cast(float, x);
}
__device__ inline unsigned short f2bf(float f) {
    return __builtin_bit_cast(unsigned short, __float2bfloat16(f));
}
__device__ inline short4v cvt4(float4 f) {
    short4v r;
    r[0] = __builtin_bit_cast(short, __float2bfloat16(f.x));
    r[1] = __builtin_bit_cast(short, __float2bfloat16(f.y));
    r[2] = __builtin_bit_cast(short, __float2bfloat16(f.z));
    r[3] = __builtin_bit_cast(short, __float2bfloat16(f.w));
    return r;
}

// ---------- Kernel 0 (fast path): normalize rows + cast to bf16 ----------
// One wave per row. Output: pre-normalized bf16 rows (unit L2 norm).
__global__ __launch_bounds__(256)
void gt_cvt_kernel(const float* __restrict__ tra, const float* __restrict__ det,
                   unsigned short* __restrict__ trab, unsigned short* __restrict__ detb)
{
    int wave = threadIdx.x >> 6, lane = threadIdx.x & 63;
    long row = (long)blockIdx.x * 4 + wave;            // 0 .. 2*G*512-1
    const long per = (long)G * MDIM;
    const float* src; unsigned short* dst; long r;
    if (row < per) { src = tra; dst = trab; r = row; }
    else           { src = det; dst = detb; r = row - per; }
    const float4* p = reinterpret_cast<const float4*>(src + r * DDIM);
    float4 x0 = p[lane];        // elements lane*4 .. +3
    float4 x1 = p[lane + 64];   // elements 256 + lane*4 .. +3
    float s = x0.x*x0.x + x0.y*x0.y + x0.z*x0.z + x0.w*x0.w
            + x1.x*x1.x + x1.y*x1.y + x1.z*x1.z + x1.w*x1.w;
    #pragma unroll
    for (int off = 1; off < 64; off <<= 1) s += __shfl_xor(s, off);
    float rs = rsqrtf(s);
    float4 y0 = make_float4(x0.x*rs, x0.y*rs, x0.z*rs, x0.w*rs);
    float4 y1 = make_float4(x1.x*rs, x1.y*rs, x1.z*rs, x1.w*rs);
    unsigned short* drow = dst + (size_t)r * 512;
    *reinterpret_cast<short4v*>(drow + lane * 4)       = cvt4(y0);
    *reinterpret_cast<short4v*>(drow + 256 + lane * 4) = cvt4(y1);
}

// ---------- Kernel 1 (fast): bf16-input GEMM -> Kexp + iter-0 column partials ----------
__global__ __launch_bounds__(256)
void gt_gemm_bf16(const unsigned short* __restrict__ trab, const unsigned short* __restrict__ detb,
                  const float* __restrict__ eps,
                  unsigned short* __restrict__ Ke, float* __restrict__ P1)
{
    __shared__ short As[128 * 40];
    __shared__ short Bs[128 * 40];
    int bid = blockIdx.x;
    int xcd = bid & 7, slot = bid >> 3;
    int g = xcd * 16 + (slot >> 4);
    int tile = slot & 15;
    int tm = tile >> 2, tn = tile & 3;
    int t = threadIdx.x, lane = t & 63, wave = t >> 6;
    int wr = wave >> 1, wc = wave & 1;
    f32x4 acc[4][4] = {};
    const unsigned short* Ab = trab + ((size_t)g << 18) + (size_t)(tm * 128) * 512;
    const unsigned short* Bb = detb + ((size_t)g << 18) + (size_t)(tn * 128) * 512;
    int srow = t >> 2;     // 0..63
    int sslot = t & 3;     // 16B slot within 32-elem K-chunk

    for (int kt = 0; kt < 16; ++kt) {
        int k0 = kt * 32;
        #pragma unroll
        for (int p = 0; p < 2; ++p) {
            int row = p * 64 + srow;
            short8 a = *reinterpret_cast<const short8*>(Ab + (size_t)row * 512 + k0 + sslot * 8);
            short8 b = *reinterpret_cast<const short8*>(Bb + (size_t)row * 512 + k0 + sslot * 8);
            *reinterpret_cast<short8*>(&As[row * 40 + sslot * 8]) = a;
            *reinterpret_cast<short8*>(&Bs[row * 40 + sslot * 8]) = b;
        }
        __syncthreads();
        short8 af[4], bfv[4];
        #pragma unroll
        for (int i = 0; i < 4; ++i) {
            int arow = wr * 64 + i * 16 + (lane & 15);
            af[i]  = *reinterpret_cast<const short8*>(&As[arow * 40 + (lane >> 4) * 8]);
            int brow = wc * 64 + i * 16 + (lane & 15);
            bfv[i] = *reinterpret_cast<const short8*>(&Bs[brow * 40 + (lane >> 4) * 8]);
        }
        #pragma unroll
        for (int i = 0; i < 4; ++i)
            #pragma unroll
            for (int j = 0; j < 4; ++j)
                acc[i][j] = __builtin_amdgcn_mfma_f32_16x16x32_bf16(af[i], bfv[j], acc[i][j], 0, 0, 0);
        __syncthreads();
    }

    float lam = __expf(eps[0]) + 0.03f;
    float nscale = -1.0f / lam;
    size_t kbase = (size_t)g << 18;
    int r0v = (lane >> 4) * 4;
    int c0 = lane & 15;
    #pragma unroll
    for (int j = 0; j < 4; ++j) {
        int lcol = wc * 64 + j * 16 + c0;
        int colg = tn * 128 + lcol;
        float cacc = 0.f;
        #pragma unroll
        for (int i = 0; i < 4; ++i) {
            int lrow = wr * 64 + i * 16 + r0v;
            #pragma unroll
            for (int r = 0; r < 4; ++r) {
                float ev = __expf(acc[i][j][r] * nscale);
                cacc += ev;
                int rowg = tm * 128 + lrow + r;
                Ke[kbase + (size_t)rowg * 512 + colg] = f2bf(ev);
            }
        }
        cacc += __shfl_down(cacc, 32);
        cacc += __shfl_down(cacc, 16);
        if (lane < 16)
            P1[(size_t)g * (8 * PW) + (size_t)(2 * tm + wr) * PW + tn * 128 + wc * 64 + j * 16 + lane] = cacc;
    }
}

// ---------- Legacy fused GEMM (slow/fallback path, f32 K into out) ----------
__global__ __launch_bounds__(256)
void gt_gemm_legacy(const float* __restrict__ tra, const float* __restrict__ det,
                    const float* __restrict__ eps,
                    float* __restrict__ Koutf, float* __restrict__ P1)
{
    __shared__ short As[128 * 40];
    __shared__ short Bs[128 * 40];
    __shared__ float rnA[128];
    __shared__ float rnB[128];
    int bid = blockIdx.x;
    int xcd = bid & 7, slot = bid >> 3;
    int g = xcd * 16 + (slot >> 4);
    int tile = slot & 15;
    int tm = tile >> 2, tn = tile & 3;
    int t = threadIdx.x, lane = t & 63, wave = t >> 6;
    int wr = wave >> 1, wc = wave & 1;
    f32x4 acc[4][4] = {};
    const float* Abase = tra + (size_t)g * MDIM * DDIM + (size_t)(tm * 128) * DDIM;
    const float* Bbase = det + (size_t)g * NDIM * DDIM + (size_t)(tn * 128) * DDIM;
    int srow = t >> 3, scol = t & 7;
    float ssA[4] = {0.f, 0.f, 0.f, 0.f};
    float ssB[4] = {0.f, 0.f, 0.f, 0.f};

    for (int kt = 0; kt < 16; ++kt) {
        int k0 = kt * 32;
        #pragma unroll
        for (int p = 0; p < 4; ++p) {
            int row = p * 32 + srow;
            float4 a = *reinterpret_cast<const float4*>(Abase + (size_t)row * DDIM + k0 + scol * 4);
            float4 b = *reinterpret_cast<const float4*>(Bbase + (size_t)row * DDIM + k0 + scol * 4);
            ssA[p] += a.x*a.x + a.y*a.y + a.z*a.z + a.w*a.w;
            ssB[p] += b.x*b.x + b.y*b.y + b.z*b.z + b.w*b.w;
            *reinterpret_cast<short4v*>(&As[row * 40 + scol * 4]) = cvt4(a);
            *reinterpret_cast<short4v*>(&Bs[row * 40 + scol * 4]) = cvt4(b);
        }
        __syncthreads();
        short8 af[4], bfv[4];
        #pragma unroll
        for (int i = 0; i < 4; ++i) {
            int arow = wr * 64 + i * 16 + (lane & 15);
            af[i]  = *reinterpret_cast<const short8*>(&As[arow * 40 + (lane >> 4) * 8]);
            int brow = wc * 64 + i * 16 + (lane & 15);
            bfv[i] = *reinterpret_cast<const short8*>(&Bs[brow * 40 + (lane >> 4) * 8]);
        }
        #pragma unroll
        for (int i = 0; i < 4; ++i)
            #pragma unroll
            for (int j = 0; j < 4; ++j)
                acc[i][j] = __builtin_amdgcn_mfma_f32_16x16x32_bf16(af[i], bfv[j], acc[i][j], 0, 0, 0);
        __syncthreads();
    }

    #pragma unroll
    for (int p = 0; p < 4; ++p) {
        float a = ssA[p], b = ssB[p];
        a += __shfl_xor(a, 1); a += __shfl_xor(a, 2); a += __shfl_xor(a, 4);
        b += __shfl_xor(b, 1); b += __shfl_xor(b, 2); b += __shfl_xor(b, 4);
        if (scol == 0) { rnA[p * 32 + srow] = rsqrtf(a); rnB[p * 32 + srow] = rsqrtf(b); }
    }
    __syncthreads();

    float lam = __expf(eps[0]) + 0.03f;
    float nscale = -1.0f / lam;
    size_t obase = (size_t)g * 263169;
    int r0v = (lane >> 4) * 4;
    int c0 = lane & 15;
    #pragma unroll
    for (int j = 0; j < 4; ++j) {
        int lcol = wc * 64 + j * 16 + c0;
        int colg = tn * 128 + lcol;
        float sc2 = nscale * rnB[lcol];
        float cacc = 0.f;
        #pragma unroll
        for (int i = 0; i < 4; ++i) {
            int lrow = wr * 64 + i * 16 + r0v;
            #pragma unroll
            for (int r = 0; r < 4; ++r) {
                float ev = __expf(acc[i][j][r] * rnA[lrow + r] * sc2);
                cacc += ev;
                int rowg = tm * 128 + lrow + r;
                Koutf[obase + (size_t)rowg * 513 + colg] = ev;
            }
        }
        cacc += __shfl_down(cacc, 32);
        cacc += __shfl_down(cacc, 16);
        if (lane < 16)
            P1[(size_t)g * (8 * PW) + (size_t)(2 * tm + wr) * PW + tn * 128 + wc * 64 + j * 16 + lane] = cacc;
    }
}

// ---------- Kernel 2 (x8): fused iteration — one pass over K ----------
template<bool BF16>
__global__ __launch_bounds__(256)
void gt_iter(const void* __restrict__ Kv,
             const float* __restrict__ alpha, const float* __restrict__ eps,
             const float* __restrict__ Pread, float* __restrict__ Pwrite,
             float* __restrict__ auOut, int first, int writeP)
{
    __shared__ float bv_s[512];
    __shared__ float colpart[4][512];
    __shared__ float rtmp[4];
    __shared__ float scal[1];
    int g = blockIdx.y, rb = blockIdx.x;
    int t = threadIdx.x, lane = t & 63, wv = t >> 6;
    float lam = __expf(eps[0]) + 0.03f;
    float val = __expf(-alpha[0] / lam);
    const float* Pg = Pread + (size_t)g * (8 * PW);
    float au512p = first ? 1.0f : Pg[513];
    float cs0 = 0.f, cs1 = 0.f;
    #pragma unroll
    for (int b = 0; b < 8; ++b) { cs0 += Pg[b * PW + t]; cs1 += Pg[b * PW + t + 256]; }
    float bv0 = NORMC / (cs0 + val * au512p);
    float bv1 = NORMC / (cs1 + val * au512p);
    bv_s[t] = bv0; bv_s[t + 256] = bv1;
    float sb = bv0 + bv1;
    #pragma unroll
    for (int off = 1; off < 64; off <<= 1) sb += __shfl_xor(sb, off);
    if (lane == 0) rtmp[wv] = sb;
    __syncthreads();
    if (t == 0) {
        float S_bv = rtmp[0] + rtmp[1] + rtmp[2] + rtmp[3];
        float S_au_prev;
        if (first) S_au_prev = 513.f;
        else { float s = 0.f; for (int b = 0; b < 8; ++b) s += Pg[b * PW + 512]; S_au_prev = s + au512p; }
        float bv512 = BINW / (val * S_au_prev);
        float au512n = BINW / (val * (S_bv + bv512));
        scal[0] = bv512;
        if (rb == 0) Pwrite[(size_t)g * (8 * PW) + 513] = au512n;
    }
    __syncthreads();
    float bv512 = scal[0];

    float bvr[8];
    #pragma unroll
    for (int k = 0; k < 8; ++k) bvr[k] = bv_s[lane * 8 + k];
    float colacc[8] = {};
    float suma = 0.f;
    const size_t RS = BF16 ? 512 : 513;
    size_t base = BF16 ? ((size_t)g << 18) : ((size_t)g * 263169);
    int rowbase = rb * 64;
    for (int rr = wv; rr < 64; rr += 4) {
        int r = rowbase + rr;
        float kv[8];
        if constexpr (BF16) {
            short8 x = *reinterpret_cast<const short8*>((const unsigned short*)Kv + base + (size_t)r * RS + lane * 8);
            #pragma unroll
            for (int k = 0; k < 8; ++k) kv[k] = bf2f((unsigned short)x[k]);
        } else {
            const float* p = (const float*)Kv + base + (size_t)r * RS + lane * 8;
            #pragma unroll
            for (int k = 0; k < 8; ++k) kv[k] = p[k];
        }
        float dot = 0.f;
        #pragma unroll
        for (int k = 0; k < 8; ++k) dot += kv[k] * bvr[k];
        #pragma unroll
        for (int off = 1; off < 64; off <<= 1) dot += __shfl_xor(dot, off);
        float au_r = NORMC / (dot + val * bv512);
        suma += au_r;
        #pragma unroll
        for (int k = 0; k < 8; ++k) colacc[k] += kv[k] * au_r;
        if (lane == 0) auOut[g * 512 + r] = au_r;
    }
    if (writeP) {
        #pragma unroll
        for (int k = 0; k < 8; ++k) colpart[wv][lane * 8 + k] = colacc[k];
        if (lane == 0) rtmp[wv] = suma;
        __syncthreads();
        float s0 = colpart[0][t] + colpart[1][t] + colpart[2][t] + colpart[3][t];
        float s1 = colpart[0][t + 256] + colpart[1][t + 256] + colpart[2][t + 256] + colpart[3][t + 256];
        float* Pw = Pwrite + (size_t)g * (8 * PW) + (size_t)rb * PW;
        Pw[t] = s0; Pw[t + 256] = s1;
        if (t == 0) Pw[512] = rtmp[0] + rtmp[1] + rtmp[2] + rtmp[3];
    }
}

// ---------- Kernel 3: finalize ----------
template<bool BF16>
__global__ __launch_bounds__(256)
void gt_final(const void* Kv, const float* __restrict__ alpha, const float* __restrict__ eps,
              const float* __restrict__ P6, const float* __restrict__ P7,
              const float* __restrict__ au, float* out)
{
    __shared__ float bv_s[512];
    __shared__ float scal[2];
    int g = blockIdx.y, rb = blockIdx.x;
    int t = threadIdx.x, lane = t & 63, wv = t >> 6;
    float lam = __expf(eps[0]) + 0.03f;
    float val = __expf(-alpha[0] / lam);
    const float* Pg = P6 + (size_t)g * (8 * PW);
    float au512_6 = Pg[513];
    float cs0 = 0.f, cs1 = 0.f;
    #pragma unroll
    for (int b = 0; b < 8; ++b) { cs0 += Pg[b * PW + t]; cs1 += Pg[b * PW + t + 256]; }
    bv_s[t] = NORMC / (cs0 + val * au512_6);
    bv_s[t + 256] = NORMC / (cs1 + val * au512_6);
    if (t == 0) {
        float s = 0.f;
        for (int b = 0; b < 8; ++b) s += Pg[b * PW + 512];
        scal[0] = BINW / (val * (s + au512_6));          // bv512(final)
        scal[1] = P7[(size_t)g * (8 * PW) + 513];        // au512(final)
    }
    __syncthreads();
    float bv512 = scal[0], au512_7 = scal[1];
    size_t base = BF16 ? ((size_t)g << 18) : ((size_t)g * 263169);
    size_t obase = (size_t)g * 263169;
    for (int rr = wv; rr < 64; rr += 4) {
        int r = rb * 64 + rr;
        float au_r = au[g * 512 + r];
        float* orow = out + obase + (size_t)r * 513;
        if constexpr (BF16) {
            const unsigned short* kr = (const unsigned short*)Kv + base + (size_t)r * 512;
            #pragma unroll
            for (int k = 0; k < 8; ++k) {
                int j = lane + 64 * k;
                orow[j] = bf2f(kr[j]) * au_r * bv_s[j];
            }
        } else {
            const float* kr = (const float*)Kv + base + (size_t)r * 513;
            #pragma unroll
            for (int k = 0; k < 8; ++k) {
                int j = lane + 64 * k;
                orow[j] = kr[j] * au_r * bv_s[j];
            }
        }
        if (lane == 0) orow[512] = val * au_r * bv512;
    }
    if (rb == 7) {
        float* brow = out + obase + (size_t)512 * 513;
        brow[t] = val * au512_7 * bv_s[t];
        brow[t + 256] = val * au512_7 * bv_s[t + 256];
        if (t == 0) brow[512] = val * au512_7 * bv512;
    }
}

extern "C" void kernel_launch(void* const* d_in, const int* in_sizes, int n_in,
                              void* d_out, int out_size, void* d_ws, size_t ws_size,
                              hipStream_t stream) {
    const float* det   = (const float*)d_in[0];
    const float* tra   = (const float*)d_in[1];
    const float* alpha = (const float*)d_in[2];
    const float* eps   = (const float*)d_in[3];
    float* out = (float*)d_out;

    float* P0 = (float*)d_ws;                       // G*8*PW f32
    float* P1 = P0 + (size_t)G * 8 * PW;            // G*8*PW f32
    float* au = P1 + (size_t)G * 8 * PW;            // G*512 f32
    unsigned short* ke = (unsigned short*)(au + (size_t)G * 512);   // G*512*512 bf16

    size_t smallBytes = ((size_t)2 * G * 8 * PW + (size_t)G * 512) * 4;
    bool fast = ws_size >= smallBytes + ((size_t)G << 19);

    if (fast) {
        // bf16 normalized inputs staged in d_out (fully overwritten by gt_final)
        unsigned short* trab = (unsigned short*)out;
        unsigned short* detb = trab + ((size_t)G << 18);
        gt_cvt_kernel<<<(2 * G * MDIM) / 4, 256, 0, stream>>>(tra, det, trab, detb);
        gt_gemm_bf16<<<2048, 256, 0, stream>>>(trab, detb, eps, ke, P1);
        float* Pr = P1; float* Pw = P0;
        for (int it = 0; it < 8; ++it) {
            gt_iter<true><<<dim3(8, G), 256, 0, stream>>>((const void*)ke, alpha, eps, Pr, Pw, au, it == 0 ? 1 : 0, it < 7 ? 1 : 0);
            float* tmp = Pr; Pr = Pw; Pw = tmp;
        }
        gt_final<true><<<dim3(8, G), 256, 0, stream>>>((const void*)ke, alpha, eps, P0, P1, au, out);
    } else {
        gt_gemm_legacy<<<2048, 256, 0, stream>>>(tra, det, eps, out, P1);
        float* Pr = P1; float* Pw = P0;
        for (int it = 0; it < 8; ++it) {
            gt_iter<false><<<dim3(8, G), 256, 0, stream>>>((const void*)out, alpha, eps, Pr, Pw, au, it == 0 ? 1 : 0, it < 7 ? 1 : 0);
            float* tmp = Pr; Pr = Pw; Pw = tmp;
        }
        gt_final<false><<<dim3(8, G), 256, 0, stream>>>((const void*)out, alpha, eps, P0, P1, au, out);
    }
}

// Round 7
// 297.485 us; speedup vs baseline: 2.4093x; 1.0473x over previous
//
#include <hip/hip_runtime.h>
#include <hip/hip_bf16.h>

#define G    128
#define MDIM 512
#define NDIM 512
#define DDIM 512
#define NORMC 0.0009765625f   // 1/(M+N)
#define BINW  0.5f            // NORMC * 512
#define PW   516              // P row width (f32): [0..511] colsums, [512] sum(au) partial, [513] au512

using short8 = __attribute__((ext_vector_type(8))) short;
using short4v = __attribute__((ext_vector_type(4))) short;
using f32x4 = __attribute__((ext_vector_type(4))) float;

__device__ inline float bf2f(unsigned short u) {
    unsigned int x = ((unsigned int)u) << 16;
    return __builtin_bit_cast(float, x);
}
__device__ inline unsigned short f2bf(float f) {
    return __builtin_bit_cast(unsigned short, __float2bfloat16(f));
}
__device__ inline short4v cvt4(float4 f) {
    short4v r;
    r[0] = __builtin_bit_cast(short, __float2bfloat16(f.x));
    r[1] = __builtin_bit_cast(short, __float2bfloat16(f.y));
    r[2] = __builtin_bit_cast(short, __float2bfloat16(f.z));
    r[3] = __builtin_bit_cast(short, __float2bfloat16(f.w));
    return r;
}

// ---------- Kernel 0 (fast path): normalize rows + cast to bf16 ----------
// One wave per 2 rows; lane owns 8 consecutive floats per row (32B loads, 16B store).
__global__ __launch_bounds__(256)
void gt_cvt_kernel(const float* __restrict__ tra, const float* __restrict__ det,
                   unsigned short* __restrict__ trab, unsigned short* __restrict__ detb)
{
    int wave = threadIdx.x >> 6, lane = threadIdx.x & 63;
    long row0 = (long)blockIdx.x * 8 + wave * 2;       // even; 0 .. 2*G*512-2
    const long per = (long)G * MDIM;                   // 65536 (even) -> no straddle
    const float* src; unsigned short* dst; long r0;
    if (row0 < per) { src = tra; dst = trab; r0 = row0; }
    else            { src = det; dst = detb; r0 = row0 - per; }
    const float4* p0 = reinterpret_cast<const float4*>(src + r0 * DDIM);
    const float4* p1 = reinterpret_cast<const float4*>(src + (r0 + 1) * DDIM);
    float4 a0 = p0[lane * 2], a1 = p0[lane * 2 + 1];
    float4 b0 = p1[lane * 2], b1 = p1[lane * 2 + 1];
    float sa = a0.x*a0.x + a0.y*a0.y + a0.z*a0.z + a0.w*a0.w
             + a1.x*a1.x + a1.y*a1.y + a1.z*a1.z + a1.w*a1.w;
    float sb = b0.x*b0.x + b0.y*b0.y + b0.z*b0.z + b0.w*b0.w
             + b1.x*b1.x + b1.y*b1.y + b1.z*b1.z + b1.w*b1.w;
    #pragma unroll
    for (int off = 1; off < 64; off <<= 1) {
        sa += __shfl_xor(sa, off);
        sb += __shfl_xor(sb, off);
    }
    float ra = rsqrtf(sa), rb = rsqrtf(sb);
    short8 oa, ob;
    {
        short4v lo = cvt4(make_float4(a0.x*ra, a0.y*ra, a0.z*ra, a0.w*ra));
        short4v hi = cvt4(make_float4(a1.x*ra, a1.y*ra, a1.z*ra, a1.w*ra));
        oa[0]=lo[0]; oa[1]=lo[1]; oa[2]=lo[2]; oa[3]=lo[3];
        oa[4]=hi[0]; oa[5]=hi[1]; oa[6]=hi[2]; oa[7]=hi[3];
    }
    {
        short4v lo = cvt4(make_float4(b0.x*rb, b0.y*rb, b0.z*rb, b0.w*rb));
        short4v hi = cvt4(make_float4(b1.x*rb, b1.y*rb, b1.z*rb, b1.w*rb));
        ob[0]=lo[0]; ob[1]=lo[1]; ob[2]=lo[2]; ob[3]=lo[3];
        ob[4]=hi[0]; ob[5]=hi[1]; ob[6]=hi[2]; ob[7]=hi[3];
    }
    *reinterpret_cast<short8*>(dst + (size_t)r0 * 512 + lane * 8)       = oa;
    *reinterpret_cast<short8*>(dst + (size_t)(r0 + 1) * 512 + lane * 8) = ob;
}

// ---------- Kernel 1 (fast): bf16-input GEMM -> Kexp + iter-0 column partials ----------
__global__ __launch_bounds__(256)
void gt_gemm_bf16(const unsigned short* __restrict__ trab, const unsigned short* __restrict__ detb,
                  const float* __restrict__ eps,
                  unsigned short* __restrict__ Ke, float* __restrict__ P1)
{
    __shared__ short As[128 * 40];
    __shared__ short Bs[128 * 40];
    int bid = blockIdx.x;
    int xcd = bid & 7, slot = bid >> 3;
    int g = xcd * 16 + (slot >> 4);
    int tile = slot & 15;
    int tm = tile >> 2, tn = tile & 3;
    int t = threadIdx.x, lane = t & 63, wave = t >> 6;
    int wr = wave >> 1, wc = wave & 1;
    f32x4 acc[4][4] = {};
    const unsigned short* Ab = trab + ((size_t)g << 18) + (size_t)(tm * 128) * 512;
    const unsigned short* Bb = detb + ((size_t)g << 18) + (size_t)(tn * 128) * 512;
    int srow = t >> 2;     // 0..63
    int sslot = t & 3;     // 16B slot within 32-elem K-chunk

    for (int kt = 0; kt < 16; ++kt) {
        int k0 = kt * 32;
        #pragma unroll
        for (int p = 0; p < 2; ++p) {
            int row = p * 64 + srow;
            short8 a = *reinterpret_cast<const short8*>(Ab + (size_t)row * 512 + k0 + sslot * 8);
            short8 b = *reinterpret_cast<const short8*>(Bb + (size_t)row * 512 + k0 + sslot * 8);
            *reinterpret_cast<short8*>(&As[row * 40 + sslot * 8]) = a;
            *reinterpret_cast<short8*>(&Bs[row * 40 + sslot * 8]) = b;
        }
        __syncthreads();
        short8 af[4], bfv[4];
        #pragma unroll
        for (int i = 0; i < 4; ++i) {
            int arow = wr * 64 + i * 16 + (lane & 15);
            af[i]  = *reinterpret_cast<const short8*>(&As[arow * 40 + (lane >> 4) * 8]);
            int brow = wc * 64 + i * 16 + (lane & 15);
            bfv[i] = *reinterpret_cast<const short8*>(&Bs[brow * 40 + (lane >> 4) * 8]);
        }
        #pragma unroll
        for (int i = 0; i < 4; ++i)
            #pragma unroll
            for (int j = 0; j < 4; ++j)
                acc[i][j] = __builtin_amdgcn_mfma_f32_16x16x32_bf16(af[i], bfv[j], acc[i][j], 0, 0, 0);
        __syncthreads();
    }

    float lam = __expf(eps[0]) + 0.03f;
    float nscale = -1.0f / lam;
    size_t kbase = (size_t)g << 18;
    int r0v = (lane >> 4) * 4;
    int c0 = lane & 15;
    #pragma unroll
    for (int j = 0; j < 4; ++j) {
        int lcol = wc * 64 + j * 16 + c0;
        int colg = tn * 128 + lcol;
        float cacc = 0.f;
        #pragma unroll
        for (int i = 0; i < 4; ++i) {
            int lrow = wr * 64 + i * 16 + r0v;
            #pragma unroll
            for (int r = 0; r < 4; ++r) {
                float ev = __expf(acc[i][j][r] * nscale);
                cacc += ev;
                int rowg = tm * 128 + lrow + r;
                Ke[kbase + (size_t)rowg * 512 + colg] = f2bf(ev);
            }
        }
        cacc += __shfl_down(cacc, 32);
        cacc += __shfl_down(cacc, 16);
        if (lane < 16)
            P1[(size_t)g * (8 * PW) + (size_t)(2 * tm + wr) * PW + tn * 128 + wc * 64 + j * 16 + lane] = cacc;
    }
}

// ---------- Legacy fused GEMM (slow/fallback path, f32 K into out) ----------
__global__ __launch_bounds__(256)
void gt_gemm_legacy(const float* __restrict__ tra, const float* __restrict__ det,
                    const float* __restrict__ eps,
                    float* __restrict__ Koutf, float* __restrict__ P1)
{
    __shared__ short As[128 * 40];
    __shared__ short Bs[128 * 40];
    __shared__ float rnA[128];
    __shared__ float rnB[128];
    int bid = blockIdx.x;
    int xcd = bid & 7, slot = bid >> 3;
    int g = xcd * 16 + (slot >> 4);
    int tile = slot & 15;
    int tm = tile >> 2, tn = tile & 3;
    int t = threadIdx.x, lane = t & 63, wave = t >> 6;
    int wr = wave >> 1, wc = wave & 1;
    f32x4 acc[4][4] = {};
    const float* Abase = tra + (size_t)g * MDIM * DDIM + (size_t)(tm * 128) * DDIM;
    const float* Bbase = det + (size_t)g * NDIM * DDIM + (size_t)(tn * 128) * DDIM;
    int srow = t >> 3, scol = t & 7;
    float ssA[4] = {0.f, 0.f, 0.f, 0.f};
    float ssB[4] = {0.f, 0.f, 0.f, 0.f};

    for (int kt = 0; kt < 16; ++kt) {
        int k0 = kt * 32;
        #pragma unroll
        for (int p = 0; p < 4; ++p) {
            int row = p * 32 + srow;
            float4 a = *reinterpret_cast<const float4*>(Abase + (size_t)row * DDIM + k0 + scol * 4);
            float4 b = *reinterpret_cast<const float4*>(Bbase + (size_t)row * DDIM + k0 + scol * 4);
            ssA[p] += a.x*a.x + a.y*a.y + a.z*a.z + a.w*a.w;
            ssB[p] += b.x*b.x + b.y*b.y + b.z*b.z + b.w*b.w;
            *reinterpret_cast<short4v*>(&As[row * 40 + scol * 4]) = cvt4(a);
            *reinterpret_cast<short4v*>(&Bs[row * 40 + scol * 4]) = cvt4(b);
        }
        __syncthreads();
        short8 af[4], bfv[4];
        #pragma unroll
        for (int i = 0; i < 4; ++i) {
            int arow = wr * 64 + i * 16 + (lane & 15);
            af[i]  = *reinterpret_cast<const short8*>(&As[arow * 40 + (lane >> 4) * 8]);
            int brow = wc * 64 + i * 16 + (lane & 15);
            bfv[i] = *reinterpret_cast<const short8*>(&Bs[brow * 40 + (lane >> 4) * 8]);
        }
        #pragma unroll
        for (int i = 0; i < 4; ++i)
            #pragma unroll
            for (int j = 0; j < 4; ++j)
                acc[i][j] = __builtin_amdgcn_mfma_f32_16x16x32_bf16(af[i], bfv[j], acc[i][j], 0, 0, 0);
        __syncthreads();
    }

    #pragma unroll
    for (int p = 0; p < 4; ++p) {
        float a = ssA[p], b = ssB[p];
        a += __shfl_xor(a, 1); a += __shfl_xor(a, 2); a += __shfl_xor(a, 4);
        b += __shfl_xor(b, 1); b += __shfl_xor(b, 2); b += __shfl_xor(b, 4);
        if (scol == 0) { rnA[p * 32 + srow] = rsqrtf(a); rnB[p * 32 + srow] = rsqrtf(b); }
    }
    __syncthreads();

    float lam = __expf(eps[0]) + 0.03f;
    float nscale = -1.0f / lam;
    size_t obase = (size_t)g * 263169;
    int r0v = (lane >> 4) * 4;
    int c0 = lane & 15;
    #pragma unroll
    for (int j = 0; j < 4; ++j) {
        int lcol = wc * 64 + j * 16 + c0;
        int colg = tn * 128 + lcol;
        float sc2 = nscale * rnB[lcol];
        float cacc = 0.f;
        #pragma unroll
        for (int i = 0; i < 4; ++i) {
            int lrow = wr * 64 + i * 16 + r0v;
            #pragma unroll
            for (int r = 0; r < 4; ++r) {
                float ev = __expf(acc[i][j][r] * rnA[lrow + r] * sc2);
                cacc += ev;
                int rowg = tm * 128 + lrow + r;
                Koutf[obase + (size_t)rowg * 513 + colg] = ev;
            }
        }
        cacc += __shfl_down(cacc, 32);
        cacc += __shfl_down(cacc, 16);
        if (lane < 16)
            P1[(size_t)g * (8 * PW) + (size_t)(2 * tm + wr) * PW + tn * 128 + wc * 64 + j * 16 + lane] = cacc;
    }
}

// ---------- Kernel 2 (x8): fused iteration — one pass over K ----------
// LAST=true: instead of writing partial colsums, writes the final transport plan rows
// (p = Ke*au*bv) directly, plus the analytic bin row/col.
template<bool BF16, bool LAST>
__global__ __launch_bounds__(256)
void gt_iter(const void* __restrict__ Kv,
             const float* __restrict__ alpha, const float* __restrict__ eps,
             const float* __restrict__ Pread, float* __restrict__ Pwrite,
             float* __restrict__ auOut, float* __restrict__ outp,
             int first, int writeP)
{
    __shared__ float bv_s[512];
    __shared__ float colpart[4][512];
    __shared__ float rtmp[4];
    __shared__ float scal[2];
    int g = blockIdx.y, rb = blockIdx.x;
    int t = threadIdx.x, lane = t & 63, wv = t >> 6;
    float lam = __expf(eps[0]) + 0.03f;
    float val = __expf(-alpha[0] / lam);
    const float* Pg = Pread + (size_t)g * (8 * PW);
    float au512p = first ? 1.0f : Pg[513];
    float cs0 = 0.f, cs1 = 0.f;
    #pragma unroll
    for (int b = 0; b < 8; ++b) { cs0 += Pg[b * PW + t]; cs1 += Pg[b * PW + t + 256]; }
    float bv0 = NORMC / (cs0 + val * au512p);
    float bv1 = NORMC / (cs1 + val * au512p);
    bv_s[t] = bv0; bv_s[t + 256] = bv1;
    float sb = bv0 + bv1;
    #pragma unroll
    for (int off = 1; off < 64; off <<= 1) sb += __shfl_xor(sb, off);
    if (lane == 0) rtmp[wv] = sb;
    __syncthreads();
    if (t == 0) {
        float S_bv = rtmp[0] + rtmp[1] + rtmp[2] + rtmp[3];
        float S_au_prev;
        if (first) S_au_prev = 513.f;
        else { float s = 0.f; for (int b = 0; b < 8; ++b) s += Pg[b * PW + 512]; S_au_prev = s + au512p; }
        float bv512 = BINW / (val * S_au_prev);
        float au512n = BINW / (val * (S_bv + bv512));
        scal[0] = bv512;
        scal[1] = au512n;
        if (!LAST && rb == 0) Pwrite[(size_t)g * (8 * PW) + 513] = au512n;
    }
    __syncthreads();
    float bv512 = scal[0];

    float bvr[8];
    #pragma unroll
    for (int k = 0; k < 8; ++k) bvr[k] = bv_s[lane * 8 + k];
    float colacc[8] = {};
    float suma = 0.f;
    const size_t RS = BF16 ? 512 : 513;
    size_t base = BF16 ? ((size_t)g << 18) : ((size_t)g * 263169);
    size_t obase = (size_t)g * 263169;
    int rowbase = rb * 64;
    for (int rr = wv; rr < 64; rr += 4) {
        int r = rowbase + rr;
        float kv[8];
        if constexpr (BF16) {
            short8 x = *reinterpret_cast<const short8*>((const unsigned short*)Kv + base + (size_t)r * RS + lane * 8);
            #pragma unroll
            for (int k = 0; k < 8; ++k) kv[k] = bf2f((unsigned short)x[k]);
        } else {
            const float* p = (const float*)Kv + base + (size_t)r * RS + lane * 8;
            #pragma unroll
            for (int k = 0; k < 8; ++k) kv[k] = p[k];
        }
        float dot = 0.f;
        #pragma unroll
        for (int k = 0; k < 8; ++k) dot += kv[k] * bvr[k];
        #pragma unroll
        for (int off = 1; off < 64; off <<= 1) dot += __shfl_xor(dot, off);
        float au_r = NORMC / (dot + val * bv512);
        if constexpr (LAST) {
            float* orow = outp + obase + (size_t)r * 513;
            f32x4 o0, o1;
            #pragma unroll
            for (int k = 0; k < 4; ++k) {
                o0[k] = kv[k] * au_r * bvr[k];
                o1[k] = kv[4 + k] * au_r * bvr[4 + k];
            }
            *reinterpret_cast<f32x4*>(orow + lane * 8)     = o0;
            *reinterpret_cast<f32x4*>(orow + lane * 8 + 4) = o1;
            if (lane == 0) orow[512] = val * au_r * bv512;
        } else {
            suma += au_r;
            #pragma unroll
            for (int k = 0; k < 8; ++k) colacc[k] += kv[k] * au_r;
            if (lane == 0) auOut[g * 512 + r] = au_r;
        }
    }
    if constexpr (LAST) {
        if (rb == 7) {
            float au512n = scal[1];
            float* brow = outp + obase + (size_t)512 * 513;
            brow[t] = val * au512n * bv_s[t];
            brow[t + 256] = val * au512n * bv_s[t + 256];
            if (t == 0) brow[512] = val * au512n * bv512;
        }
    } else if (writeP) {
        #pragma unroll
        for (int k = 0; k < 8; ++k) colpart[wv][lane * 8 + k] = colacc[k];
        if (lane == 0) rtmp[wv] = suma;
        __syncthreads();
        float s0 = colpart[0][t] + colpart[1][t] + colpart[2][t] + colpart[3][t];
        float s1 = colpart[0][t + 256] + colpart[1][t + 256] + colpart[2][t + 256] + colpart[3][t + 256];
        float* Pw = Pwrite + (size_t)g * (8 * PW) + (size_t)rb * PW;
        Pw[t] = s0; Pw[t + 256] = s1;
        if (t == 0) Pw[512] = rtmp[0] + rtmp[1] + rtmp[2] + rtmp[3];
    }
}

extern "C" void kernel_launch(void* const* d_in, const int* in_sizes, int n_in,
                              void* d_out, int out_size, void* d_ws, size_t ws_size,
                              hipStream_t stream) {
    const float* det   = (const float*)d_in[0];
    const float* tra   = (const float*)d_in[1];
    const float* alpha = (const float*)d_in[2];
    const float* eps   = (const float*)d_in[3];
    float* out = (float*)d_out;

    float* P0 = (float*)d_ws;                       // G*8*PW f32
    float* P1 = P0 + (size_t)G * 8 * PW;            // G*8*PW f32
    float* au = P1 + (size_t)G * 8 * PW;            // G*512 f32
    unsigned short* ke = (unsigned short*)(au + (size_t)G * 512);   // G*512*512 bf16

    size_t smallBytes = ((size_t)2 * G * 8 * PW + (size_t)G * 512) * 4;
    bool fast = ws_size >= smallBytes + ((size_t)G << 19);

    if (fast) {
        // bf16 normalized inputs staged in d_out (fully overwritten by the last iter)
        unsigned short* trab = (unsigned short*)out;
        unsigned short* detb = trab + ((size_t)G << 18);
        gt_cvt_kernel<<<(2 * G * MDIM) / 8, 256, 0, stream>>>(tra, det, trab, detb);
        gt_gemm_bf16<<<2048, 256, 0, stream>>>(trab, detb, eps, ke, P1);
        float* Pr = P1; float* Pw = P0;
        for (int it = 0; it < 7; ++it) {
            gt_iter<true, false><<<dim3(8, G), 256, 0, stream>>>((const void*)ke, alpha, eps, Pr, Pw, au, nullptr, it == 0 ? 1 : 0, 1);
            float* tmp = Pr; Pr = Pw; Pw = tmp;
        }
        gt_iter<true, true><<<dim3(8, G), 256, 0, stream>>>((const void*)ke, alpha, eps, Pr, Pw, au, out, 0, 0);
    } else {
        gt_gemm_legacy<<<2048, 256, 0, stream>>>(tra, det, eps, out, P1);
        float* Pr = P1; float* Pw = P0;
        for (int it = 0; it < 7; ++it) {
            gt_iter<false, false><<<dim3(8, G), 256, 0, stream>>>((const void*)out, alpha, eps, Pr, Pw, au, nullptr, it == 0 ? 1 : 0, 1);
            float* tmp = Pr; Pr = Pw; Pw = tmp;
        }
        gt_iter<false, true><<<dim3(8, G), 256, 0, stream>>>((const void*)out, alpha, eps, Pr, Pw, au, out, 0, 0);
    }
}

// Round 8
// 286.071 us; speedup vs baseline: 2.5054x; 1.0399x over previous
//
#include <hip/hip_runtime.h>
#include <hip/hip_bf16.h>

#define G    128
#define MDIM 512
#define NDIM 512
#define DDIM 512
#define NORMC 0.0009765625f   // 1/(M+N)
#define BINW  0.5f            // NORMC * 512
#define PW   516              // P row width (f32): [0..511] colsums, [512] sum(au) partial, [513] au512

using short8 = __attribute__((ext_vector_type(8))) short;
using short4v = __attribute__((ext_vector_type(4))) short;
using f32x4 = __attribute__((ext_vector_type(4))) float;

__device__ inline float bf2f(unsigned short u) {
    unsigned int x = ((unsigned int)u) << 16;
    return __builtin_bit_cast(float, x);
}
__device__ inline unsigned short f2bf(float f) {
    return __builtin_bit_cast(unsigned short, __float2bfloat16(f));
}
__device__ inline short4v cvt4(float4 f) {
    short4v r;
    r[0] = __builtin_bit_cast(short, __float2bfloat16(f.x));
    r[1] = __builtin_bit_cast(short, __float2bfloat16(f.y));
    r[2] = __builtin_bit_cast(short, __float2bfloat16(f.z));
    r[3] = __builtin_bit_cast(short, __float2bfloat16(f.w));
    return r;
}

// ---------- Kernel 0 (fast path): normalize rows + cast to bf16 ----------
// 4 rows per wave: 8 independent 32B loads in flight, 4 interleaved butterflies.
__global__ __launch_bounds__(256)
void gt_cvt_kernel(const float* __restrict__ tra, const float* __restrict__ det,
                   unsigned short* __restrict__ trab, unsigned short* __restrict__ detb)
{
    int wave = threadIdx.x >> 6, lane = threadIdx.x & 63;
    long row0 = ((long)blockIdx.x * 4 + wave) * 4;     // multiple of 4
    const long per = (long)G * MDIM;                   // 65536 -> no straddle (div by 4)
    const float* src; unsigned short* dst; long r0;
    if (row0 < per) { src = tra; dst = trab; r0 = row0; }
    else            { src = det; dst = detb; r0 = row0 - per; }
    float4 x0[4], x1[4];
    #pragma unroll
    for (int r = 0; r < 4; ++r) {
        const float4* p = reinterpret_cast<const float4*>(src + (size_t)(r0 + r) * DDIM);
        x0[r] = p[lane * 2];
        x1[r] = p[lane * 2 + 1];
    }
    float s[4];
    #pragma unroll
    for (int r = 0; r < 4; ++r)
        s[r] = x0[r].x*x0[r].x + x0[r].y*x0[r].y + x0[r].z*x0[r].z + x0[r].w*x0[r].w
             + x1[r].x*x1[r].x + x1[r].y*x1[r].y + x1[r].z*x1[r].z + x1[r].w*x1[r].w;
    #pragma unroll
    for (int off = 1; off < 64; off <<= 1) {
        #pragma unroll
        for (int r = 0; r < 4; ++r) s[r] += __shfl_xor(s[r], off);
    }
    #pragma unroll
    for (int r = 0; r < 4; ++r) {
        float rs = rsqrtf(s[r]);
        short4v lo = cvt4(make_float4(x0[r].x*rs, x0[r].y*rs, x0[r].z*rs, x0[r].w*rs));
        short4v hi = cvt4(make_float4(x1[r].x*rs, x1[r].y*rs, x1[r].z*rs, x1[r].w*rs));
        short8 o;
        o[0]=lo[0]; o[1]=lo[1]; o[2]=lo[2]; o[3]=lo[3];
        o[4]=hi[0]; o[5]=hi[1]; o[6]=hi[2]; o[7]=hi[3];
        *reinterpret_cast<short8*>(dst + (size_t)(r0 + r) * 512 + lane * 8) = o;
    }
}

// ---------- Kernel 1 (fast): bf16-input GEMM -> Kexp + iter-0 column partials ----------
__global__ __launch_bounds__(256)
void gt_gemm_bf16(const unsigned short* __restrict__ trab, const unsigned short* __restrict__ detb,
                  const float* __restrict__ eps,
                  unsigned short* __restrict__ Ke, float* __restrict__ P1)
{
    __shared__ short As[128 * 40];
    __shared__ short Bs[128 * 40];
    int bid = blockIdx.x;
    int xcd = bid & 7, slot = bid >> 3;
    int g = xcd * 16 + (slot >> 4);
    int tile = slot & 15;
    int tm = tile >> 2, tn = tile & 3;
    int t = threadIdx.x, lane = t & 63, wave = t >> 6;
    int wr = wave >> 1, wc = wave & 1;
    f32x4 acc[4][4] = {};
    const unsigned short* Ab = trab + ((size_t)g << 18) + (size_t)(tm * 128) * 512;
    const unsigned short* Bb = detb + ((size_t)g << 18) + (size_t)(tn * 128) * 512;
    int srow = t >> 2;     // 0..63
    int sslot = t & 3;     // 16B slot within 32-elem K-chunk

    for (int kt = 0; kt < 16; ++kt) {
        int k0 = kt * 32;
        #pragma unroll
        for (int p = 0; p < 2; ++p) {
            int row = p * 64 + srow;
            short8 a = *reinterpret_cast<const short8*>(Ab + (size_t)row * 512 + k0 + sslot * 8);
            short8 b = *reinterpret_cast<const short8*>(Bb + (size_t)row * 512 + k0 + sslot * 8);
            *reinterpret_cast<short8*>(&As[row * 40 + sslot * 8]) = a;
            *reinterpret_cast<short8*>(&Bs[row * 40 + sslot * 8]) = b;
        }
        __syncthreads();
        short8 af[4], bfv[4];
        #pragma unroll
        for (int i = 0; i < 4; ++i) {
            int arow = wr * 64 + i * 16 + (lane & 15);
            af[i]  = *reinterpret_cast<const short8*>(&As[arow * 40 + (lane >> 4) * 8]);
            int brow = wc * 64 + i * 16 + (lane & 15);
            bfv[i] = *reinterpret_cast<const short8*>(&Bs[brow * 40 + (lane >> 4) * 8]);
        }
        #pragma unroll
        for (int i = 0; i < 4; ++i)
            #pragma unroll
            for (int j = 0; j < 4; ++j)
                acc[i][j] = __builtin_amdgcn_mfma_f32_16x16x32_bf16(af[i], bfv[j], acc[i][j], 0, 0, 0);
        __syncthreads();
    }

    float lam = __expf(eps[0]) + 0.03f;
    float nscale = -1.0f / lam;
    size_t kbase = (size_t)g << 18;
    int r0v = (lane >> 4) * 4;
    int c0 = lane & 15;
    #pragma unroll
    for (int j = 0; j < 4; ++j) {
        int lcol = wc * 64 + j * 16 + c0;
        int colg = tn * 128 + lcol;
        float cacc = 0.f;
        #pragma unroll
        for (int i = 0; i < 4; ++i) {
            int lrow = wr * 64 + i * 16 + r0v;
            #pragma unroll
            for (int r = 0; r < 4; ++r) {
                float ev = __expf(acc[i][j][r] * nscale);
                cacc += ev;
                int rowg = tm * 128 + lrow + r;
                Ke[kbase + (size_t)rowg * 512 + colg] = f2bf(ev);
            }
        }
        cacc += __shfl_down(cacc, 32);
        cacc += __shfl_down(cacc, 16);
        if (lane < 16)
            P1[(size_t)g * (8 * PW) + (size_t)(2 * tm + wr) * PW + tn * 128 + wc * 64 + j * 16 + lane] = cacc;
    }
}

// ---------- Legacy fused GEMM (slow/fallback path, f32 K into out) ----------
__global__ __launch_bounds__(256)
void gt_gemm_legacy(const float* __restrict__ tra, const float* __restrict__ det,
                    const float* __restrict__ eps,
                    float* __restrict__ Koutf, float* __restrict__ P1)
{
    __shared__ short As[128 * 40];
    __shared__ short Bs[128 * 40];
    __shared__ float rnA[128];
    __shared__ float rnB[128];
    int bid = blockIdx.x;
    int xcd = bid & 7, slot = bid >> 3;
    int g = xcd * 16 + (slot >> 4);
    int tile = slot & 15;
    int tm = tile >> 2, tn = tile & 3;
    int t = threadIdx.x, lane = t & 63, wave = t >> 6;
    int wr = wave >> 1, wc = wave & 1;
    f32x4 acc[4][4] = {};
    const float* Abase = tra + (size_t)g * MDIM * DDIM + (size_t)(tm * 128) * DDIM;
    const float* Bbase = det + (size_t)g * NDIM * DDIM + (size_t)(tn * 128) * DDIM;
    int srow = t >> 3, scol = t & 7;
    float ssA[4] = {0.f, 0.f, 0.f, 0.f};
    float ssB[4] = {0.f, 0.f, 0.f, 0.f};

    for (int kt = 0; kt < 16; ++kt) {
        int k0 = kt * 32;
        #pragma unroll
        for (int p = 0; p < 4; ++p) {
            int row = p * 32 + srow;
            float4 a = *reinterpret_cast<const float4*>(Abase + (size_t)row * DDIM + k0 + scol * 4);
            float4 b = *reinterpret_cast<const float4*>(Bbase + (size_t)row * DDIM + k0 + scol * 4);
            ssA[p] += a.x*a.x + a.y*a.y + a.z*a.z + a.w*a.w;
            ssB[p] += b.x*b.x + b.y*b.y + b.z*b.z + b.w*b.w;
            *reinterpret_cast<short4v*>(&As[row * 40 + scol * 4]) = cvt4(a);
            *reinterpret_cast<short4v*>(&Bs[row * 40 + scol * 4]) = cvt4(b);
        }
        __syncthreads();
        short8 af[4], bfv[4];
        #pragma unroll
        for (int i = 0; i < 4; ++i) {
            int arow = wr * 64 + i * 16 + (lane & 15);
            af[i]  = *reinterpret_cast<const short8*>(&As[arow * 40 + (lane >> 4) * 8]);
            int brow = wc * 64 + i * 16 + (lane & 15);
            bfv[i] = *reinterpret_cast<const short8*>(&Bs[brow * 40 + (lane >> 4) * 8]);
        }
        #pragma unroll
        for (int i = 0; i < 4; ++i)
            #pragma unroll
            for (int j = 0; j < 4; ++j)
                acc[i][j] = __builtin_amdgcn_mfma_f32_16x16x32_bf16(af[i], bfv[j], acc[i][j], 0, 0, 0);
        __syncthreads();
    }

    #pragma unroll
    for (int p = 0; p < 4; ++p) {
        float a = ssA[p], b = ssB[p];
        a += __shfl_xor(a, 1); a += __shfl_xor(a, 2); a += __shfl_xor(a, 4);
        b += __shfl_xor(b, 1); b += __shfl_xor(b, 2); b += __shfl_xor(b, 4);
        if (scol == 0) { rnA[p * 32 + srow] = rsqrtf(a); rnB[p * 32 + srow] = rsqrtf(b); }
    }
    __syncthreads();

    float lam = __expf(eps[0]) + 0.03f;
    float nscale = -1.0f / lam;
    size_t obase = (size_t)g * 263169;
    int r0v = (lane >> 4) * 4;
    int c0 = lane & 15;
    #pragma unroll
    for (int j = 0; j < 4; ++j) {
        int lcol = wc * 64 + j * 16 + c0;
        int colg = tn * 128 + lcol;
        float sc2 = nscale * rnB[lcol];
        float cacc = 0.f;
        #pragma unroll
        for (int i = 0; i < 4; ++i) {
            int lrow = wr * 64 + i * 16 + r0v;
            #pragma unroll
            for (int r = 0; r < 4; ++r) {
                float ev = __expf(acc[i][j][r] * rnA[lrow + r] * sc2);
                cacc += ev;
                int rowg = tm * 128 + lrow + r;
                Koutf[obase + (size_t)rowg * 513 + colg] = ev;
            }
        }
        cacc += __shfl_down(cacc, 32);
        cacc += __shfl_down(cacc, 16);
        if (lane < 16)
            P1[(size_t)g * (8 * PW) + (size_t)(2 * tm + wr) * PW + tn * 128 + wc * 64 + j * 16 + lane] = cacc;
    }
}

// ---------- Kernel 2 (x8): fused iteration, 512 threads (8 waves, 8 rows/wave) ----------
// LAST=true: writes the final transport plan rows directly instead of partial colsums.
template<bool BF16, bool LAST>
__global__ __launch_bounds__(512)
void gt_iter(const void* __restrict__ Kv,
             const float* __restrict__ alpha, const float* __restrict__ eps,
             const float* __restrict__ Pread, float* __restrict__ Pwrite,
             float* __restrict__ outp, int first, int writeP)
{
    __shared__ float bv_s[512];
    __shared__ float colpart[8][512];
    __shared__ float rtmp[8];
    __shared__ float scal[2];
    int g = blockIdx.y, rb = blockIdx.x;
    int t = threadIdx.x, lane = t & 63, wv = t >> 6;
    float lam = __expf(eps[0]) + 0.03f;
    float val = __expf(-alpha[0] / lam);
    const float* Pg = Pread + (size_t)g * (8 * PW);
    float au512p = first ? 1.0f : Pg[513];
    // head: one column per thread
    float cs = 0.f;
    #pragma unroll
    for (int b = 0; b < 8; ++b) cs += Pg[b * PW + t];
    float bvt = NORMC / (cs + val * au512p);
    bv_s[t] = bvt;
    float sb = bvt;
    #pragma unroll
    for (int off = 1; off < 64; off <<= 1) sb += __shfl_xor(sb, off);
    if (lane == 0) rtmp[wv] = sb;
    __syncthreads();
    if (t == 0) {
        float S_bv = 0.f;
        #pragma unroll
        for (int w = 0; w < 8; ++w) S_bv += rtmp[w];
        float S_au_prev;
        if (first) S_au_prev = 513.f;
        else { float s = 0.f; for (int b = 0; b < 8; ++b) s += Pg[b * PW + 512]; S_au_prev = s + au512p; }
        float bv512 = BINW / (val * S_au_prev);
        float au512n = BINW / (val * (S_bv + bv512));
        scal[0] = bv512;
        scal[1] = au512n;
        if (!LAST && rb == 0) Pwrite[(size_t)g * (8 * PW) + 513] = au512n;
    }
    __syncthreads();
    float bv512 = scal[0];

    float bvr[8];
    #pragma unroll
    for (int k = 0; k < 8; ++k) bvr[k] = bv_s[lane * 8 + k];
    float colacc[8] = {};
    float suma = 0.f;
    const size_t RS = BF16 ? 512 : 513;
    size_t base = BF16 ? ((size_t)g << 18) : ((size_t)g * 263169);
    size_t obase = (size_t)g * 263169;
    int rowbase = rb * 64;
    for (int rr = wv; rr < 64; rr += 8) {
        int r = rowbase + rr;
        float kv[8];
        if constexpr (BF16) {
            short8 x = *reinterpret_cast<const short8*>((const unsigned short*)Kv + base + (size_t)r * RS + lane * 8);
            #pragma unroll
            for (int k = 0; k < 8; ++k) kv[k] = bf2f((unsigned short)x[k]);
        } else {
            const float* p = (const float*)Kv + base + (size_t)r * RS + lane * 8;
            #pragma unroll
            for (int k = 0; k < 8; ++k) kv[k] = p[k];
        }
        float dot = 0.f;
        #pragma unroll
        for (int k = 0; k < 8; ++k) dot += kv[k] * bvr[k];
        #pragma unroll
        for (int off = 1; off < 64; off <<= 1) dot += __shfl_xor(dot, off);
        float au_r = NORMC / (dot + val * bv512);
        if constexpr (LAST) {
            float* orow = outp + obase + (size_t)r * 513;
            f32x4 o0, o1;
            #pragma unroll
            for (int k = 0; k < 4; ++k) {
                o0[k] = kv[k] * au_r * bvr[k];
                o1[k] = kv[4 + k] * au_r * bvr[4 + k];
            }
            *reinterpret_cast<f32x4*>(orow + lane * 8)     = o0;
            *reinterpret_cast<f32x4*>(orow + lane * 8 + 4) = o1;
            if (lane == 0) orow[512] = val * au_r * bv512;
        } else {
            suma += au_r;
            #pragma unroll
            for (int k = 0; k < 8; ++k) colacc[k] += kv[k] * au_r;
        }
    }
    if constexpr (LAST) {
        if (rb == 7) {
            float au512n = scal[1];
            float* brow = outp + obase + (size_t)512 * 513;
            brow[t] = val * au512n * bv_s[t];
            if (t == 0) brow[512] = val * au512n * bv512;
        }
    } else if (writeP) {
        #pragma unroll
        for (int k = 0; k < 8; ++k) colpart[wv][lane * 8 + k] = colacc[k];
        if (lane == 0) rtmp[wv] = suma;
        __syncthreads();
        float s0 = 0.f;
        #pragma unroll
        for (int w = 0; w < 8; ++w) s0 += colpart[w][t];
        float* Pw = Pwrite + (size_t)g * (8 * PW) + (size_t)rb * PW;
        Pw[t] = s0;
        if (t == 0) {
            float ss = 0.f;
            #pragma unroll
            for (int w = 0; w < 8; ++w) ss += rtmp[w];
            Pw[512] = ss;
        }
    }
}

extern "C" void kernel_launch(void* const* d_in, const int* in_sizes, int n_in,
                              void* d_out, int out_size, void* d_ws, size_t ws_size,
                              hipStream_t stream) {
    const float* det   = (const float*)d_in[0];
    const float* tra   = (const float*)d_in[1];
    const float* alpha = (const float*)d_in[2];
    const float* eps   = (const float*)d_in[3];
    float* out = (float*)d_out;

    float* P0 = (float*)d_ws;                       // G*8*PW f32
    float* P1 = P0 + (size_t)G * 8 * PW;            // G*8*PW f32
    unsigned short* ke = (unsigned short*)(P1 + (size_t)G * 8 * PW);   // G*512*512 bf16

    size_t smallBytes = (size_t)2 * G * 8 * PW * 4;
    bool fast = ws_size >= smallBytes + ((size_t)G << 19);

    if (fast) {
        // bf16 normalized inputs staged in d_out (fully overwritten by the last iter)
        unsigned short* trab = (unsigned short*)out;
        unsigned short* detb = trab + ((size_t)G << 18);
        gt_cvt_kernel<<<(2 * G * MDIM) / 16, 256, 0, stream>>>(tra, det, trab, detb);
        gt_gemm_bf16<<<2048, 256, 0, stream>>>(trab, detb, eps, ke, P1);
        float* Pr = P1; float* Pw = P0;
        for (int it = 0; it < 7; ++it) {
            gt_iter<true, false><<<dim3(8, G), 512, 0, stream>>>((const void*)ke, alpha, eps, Pr, Pw, nullptr, it == 0 ? 1 : 0, 1);
            float* tmp = Pr; Pr = Pw; Pw = tmp;
        }
        gt_iter<true, true><<<dim3(8, G), 512, 0, stream>>>((const void*)ke, alpha, eps, Pr, Pw, out, 0, 0);
    } else {
        gt_gemm_legacy<<<2048, 256, 0, stream>>>(tra, det, eps, out, P1);
        float* Pr = P1; float* Pw = P0;
        for (int it = 0; it < 7; ++it) {
            gt_iter<false, false><<<dim3(8, G), 512, 0, stream>>>((const void*)out, alpha, eps, Pr, Pw, nullptr, it == 0 ? 1 : 0, 1);
            float* tmp = Pr; Pr = Pw; Pw = tmp;
        }
        gt_iter<false, true><<<dim3(8, G), 512, 0, stream>>>((const void*)out, alpha, eps, Pr, Pw, out, 0, 0);
    }
}